// Round 1
// baseline (6278.519 us; speedup 1.0000x reference)
//
#include <hip/hip_runtime.h>
#include <math.h>

#define Bn   4096
#define Dn   768
#define Cn   80
#define H1n  256
#define H2n  64
#define H3n  16
#define H4n  4
#define TBr  32      // batch rows per block
#define KCk  32      // K-chunk for layer 1

// LDS plan (union; phases separated by __syncthreads):
//  phase1: As[32][36] (hidden chunk, transposed, padded) + Bs[32][256] (W1 chunk)  = 37.4 KB
//  phase2: xs[256][36] (relu(x1), transposed, padded)   + w2s[64][65]             = 53.5 KB
//  phase3: xs2[32][65] (relu(x2))
struct P1 { float As[KCk][36]; float Bs[KCk][H1n]; };
struct P2 { float xs[H1n][36]; float w2s[H2n][H2n + 1]; };
union SmemU { P1 p1; P2 p2; float xs2[TBr][H2n + 1]; };

__global__ __launch_bounds__(256)
void scores_kernel(const float* __restrict__ hidden,
                   const float* __restrict__ W1, const float* __restrict__ b1,
                   const float* __restrict__ W2, const float* __restrict__ b2,
                   const float* __restrict__ W3, const float* __restrict__ b3,
                   const float* __restrict__ W4, const float* __restrict__ b4,
                   const float* __restrict__ W5, const float* __restrict__ b5,
                   const float* __restrict__ rW1, const float* __restrict__ rb1,
                   const float* __restrict__ rW2, const float* __restrict__ rb2,
                   const float* __restrict__ rW3, const float* __restrict__ rb3,
                   const float* __restrict__ rW4, const float* __restrict__ rb4,
                   const float* __restrict__ rW5, const float* __restrict__ rb5,
                   float* __restrict__ scores)
{
    __shared__ SmemU sm;
    const int t   = threadIdx.x;
    const int b0  = blockIdx.x * TBr;
    const int c   = blockIdx.y;
    const int set = blockIdx.z;

    const float* pW1 = set ? rW1 : W1;  const float* pb1 = set ? rb1 : b1;
    const float* pW2 = set ? rW2 : W2;  const float* pb2 = set ? rb2 : b2;
    const float* pW3 = set ? rW3 : W3;  const float* pb3 = set ? rb3 : b3;
    const float* pW4 = set ? rW4 : W4;  const float* pb4 = set ? rb4 : b4;
    const float* pW5 = set ? rW5 : W5;  const float* pb5 = set ? rb5 : b5;

    // ---------------- phase 1: x1 = hidden[b0:b0+32] @ W1[c] + b1[c], relu  (32 x 256)
    const int tyg = t >> 6;   // 0..3 -> output rows tyg*8 .. tyg*8+7
    const int txg = t & 63;   // output cols txg*4 .. txg*4+3
    float acc[8][4];
    #pragma unroll
    for (int i = 0; i < 8; ++i)
        #pragma unroll
        for (int j = 0; j < 4; ++j) acc[i][j] = 0.f;

    for (int k0 = 0; k0 < Dn; k0 += KCk) {
        __syncthreads();
        {   // stage hidden chunk transposed: As[k][r]   (256 float4 loads, 1/thread)
            const int r = t >> 3, kq = t & 7;
            const float4 v = *(const float4*)&hidden[(size_t)(b0 + r) * Dn + k0 + kq * 4];
            sm.p1.As[kq * 4 + 0][r] = v.x;
            sm.p1.As[kq * 4 + 1][r] = v.y;
            sm.p1.As[kq * 4 + 2][r] = v.z;
            sm.p1.As[kq * 4 + 3][r] = v.w;
        }
        {   // stage W1 chunk: Bs[k][n]   (2048 float4, 8/thread)
            const float* wrow = pW1 + ((size_t)c * Dn + k0) * H1n;
            #pragma unroll
            for (int q = 0; q < 8; ++q) {
                const int idx4 = q * 256 + t;
                const int k = idx4 >> 6, n4 = idx4 & 63;
                *(float4*)&sm.p1.Bs[k][n4 * 4] =
                    *(const float4*)&wrow[(size_t)k * H1n + n4 * 4];
            }
        }
        __syncthreads();
        #pragma unroll 8
        for (int k = 0; k < KCk; ++k) {
            const float4 a0 = *(const float4*)&sm.p1.As[k][tyg * 8];
            const float4 a1 = *(const float4*)&sm.p1.As[k][tyg * 8 + 4];
            const float4 bv = *(const float4*)&sm.p1.Bs[k][txg * 4];
            const float av[8] = {a0.x, a0.y, a0.z, a0.w, a1.x, a1.y, a1.z, a1.w};
            const float bw[4] = {bv.x, bv.y, bv.z, bv.w};
            #pragma unroll
            for (int i = 0; i < 8; ++i)
                #pragma unroll
                for (int j = 0; j < 4; ++j)
                    acc[i][j] = fmaf(av[i], bw[j], acc[i][j]);
        }
    }
    __syncthreads();   // all As/Bs reads done before union repurpose
    {
        const float* pb1c = pb1 + (size_t)c * H1n;
        #pragma unroll
        for (int i = 0; i < 8; ++i) {
            const int r = tyg * 8 + i;
            #pragma unroll
            for (int j = 0; j < 4; ++j) {
                const int n = txg * 4 + j;
                sm.p2.xs[n][r] = fmaxf(acc[i][j] + pb1c[n], 0.f);  // store transposed [h][r]
            }
        }
    }
    __syncthreads();

    // ---------------- phase 2: x2 = relu(x1) @ W2[c] + b2[c], relu  (32 x 64)
    const int col  = t & 63;   // output col
    const int tyg2 = t >> 6;   // output rows tyg2*8 .. +7
    float acc2[8];
    #pragma unroll
    for (int i = 0; i < 8; ++i) acc2[i] = 0.f;

    for (int k02 = 0; k02 < H1n; k02 += 64) {
        __syncthreads();
        {   // stage W2 chunk: w2s[k][n], pad 65 (scalar stores)
            const float* w2row = pW2 + ((size_t)c * H1n + k02) * H2n;
            #pragma unroll
            for (int q = 0; q < 4; ++q) {
                const int idx4 = q * 256 + t;
                const int k = idx4 >> 4, n4 = idx4 & 15;
                const float4 v = *(const float4*)&w2row[(size_t)k * H2n + n4 * 4];
                sm.p2.w2s[k][n4 * 4 + 0] = v.x;
                sm.p2.w2s[k][n4 * 4 + 1] = v.y;
                sm.p2.w2s[k][n4 * 4 + 2] = v.z;
                sm.p2.w2s[k][n4 * 4 + 3] = v.w;
            }
        }
        __syncthreads();
        #pragma unroll 8
        for (int k = 0; k < 64; ++k) {
            const float4 a0 = *(const float4*)&sm.p2.xs[k02 + k][tyg2 * 8];
            const float4 a1 = *(const float4*)&sm.p2.xs[k02 + k][tyg2 * 8 + 4];
            const float wv = sm.p2.w2s[k][col];
            acc2[0] = fmaf(a0.x, wv, acc2[0]);
            acc2[1] = fmaf(a0.y, wv, acc2[1]);
            acc2[2] = fmaf(a0.z, wv, acc2[2]);
            acc2[3] = fmaf(a0.w, wv, acc2[3]);
            acc2[4] = fmaf(a1.x, wv, acc2[4]);
            acc2[5] = fmaf(a1.y, wv, acc2[5]);
            acc2[6] = fmaf(a1.z, wv, acc2[6]);
            acc2[7] = fmaf(a1.w, wv, acc2[7]);
        }
    }
    __syncthreads();   // all xs/w2s reads done
    {
        const float bb = pb2[(size_t)c * H2n + col];
        #pragma unroll
        for (int i = 0; i < 8; ++i)
            sm.xs2[tyg2 * 8 + i][col] = fmaxf(acc2[i] + bb, 0.f);
    }
    __syncthreads();

    // ---------------- phases 3-5: 64->16->4->1, one lane per row
    if (t < TBr) {
        const int r = t;
        const float* pW3c = pW3 + (size_t)c * (H2n * H3n);
        const float* pb3c = pb3 + (size_t)c * H3n;
        float x3r[H3n];
        #pragma unroll
        for (int n = 0; n < H3n; ++n) x3r[n] = pb3c[n];
        for (int k = 0; k < H2n; ++k) {
            const float xv = sm.xs2[r][k];                 // already relu'd
            #pragma unroll
            for (int n = 0; n < H3n; ++n)
                x3r[n] = fmaf(xv, pW3c[k * H3n + n], x3r[n]);
        }
        const float* pW4c = pW4 + (size_t)c * (H3n * H4n);
        const float* pb4c = pb4 + (size_t)c * H4n;
        float x4r[H4n];
        #pragma unroll
        for (int n = 0; n < H4n; ++n) x4r[n] = pb4c[n];
        #pragma unroll
        for (int k = 0; k < H3n; ++k) {
            const float xv = fmaxf(x3r[k], 0.f);
            #pragma unroll
            for (int n = 0; n < H4n; ++n)
                x4r[n] = fmaf(xv, pW4c[k * H4n + n], x4r[n]);
        }
        float x5 = pb5[c];
        #pragma unroll
        for (int k = 0; k < H4n; ++k)
            x5 = fmaf(fmaxf(x4r[k], 0.f), pW5[(size_t)c * H4n + k], x5);
        const float sc = 1.f / (1.f + expf(-x5));
        scores[((size_t)set * Bn + (b0 + r)) * Cn + c] = sc;
    }
}

__device__ inline float bce_f(float p, float y) {
    p = fminf(fmaxf(p, 1e-8f), 1.0f - 1e-8f);   // 1.0f-1e-8f rounds to 1.0f, same as JAX f32
    return -(y * logf(p) + (1.f - y) * log1pf(-p));
}

// one block per batch row; lanes 0..79 own one class each
__global__ __launch_bounds__(128)
void loss_kernel(const float* __restrict__ scores, const int* __restrict__ labels,
                 float* __restrict__ pair_sum, float* __restrict__ np_sum,
                 int* __restrict__ pair_cnt)
{
    __shared__ float ss[Cn], lt[Cn];
    __shared__ int lab[Cn];
    __shared__ float redf[128], redn[128];
    __shared__ int redi[128];

    const int b = blockIdx.x, t = threadIdx.x;
    float np_local = 0.f, ps_local = 0.f;
    int pc_local = 0;

    if (t < Cn) {
        const float s  = scores[(size_t)b * Cn + t];
        const float sr = scores[(size_t)Bn * Cn + (size_t)b * Cn + t];
        const int l = labels[(size_t)b * Cn + t];
        ss[t] = s; lab[t] = l;
        lt[t] = logf(s / (sr + 1e-8f) + 1e-8f);
        if (t >= 20) {   // nonpriv BCE margin
            const float y = (float)l;
            np_local = fmaxf(bce_f(s, y) - bce_f(sr, y) - 0.1f, 0.f);
        }
    }
    __syncthreads();
    if (t < Cn && lab[t] == 0) {   // j = t, neg[j]
        const float sj = ss[t], ltj = lt[t];
        #pragma unroll
        for (int i = 0; i < 20; ++i) {
            if (lab[i] == 1 && sj >= ss[i]) {
                const float z = -(lt[i] - ltj);          // -h_w
                ps_local += fmaxf(z, 0.f) + log1pf(expf(-fabsf(z)));  // softplus(-h) = -log_sigmoid(h)
                pc_local++;
            }
        }
    }
    redf[t] = ps_local; redn[t] = np_local; redi[t] = pc_local;
    __syncthreads();
    for (int s = 64; s > 0; s >>= 1) {
        if (t < s) { redf[t] += redf[t + s]; redn[t] += redn[t + s]; redi[t] += redi[t + s]; }
        __syncthreads();
    }
    if (t == 0) { pair_sum[b] = redf[0]; np_sum[b] = redn[0]; pair_cnt[b] = redi[0]; }
}

__global__ __launch_bounds__(256)
void final_kernel(const float* __restrict__ pair_sum, const int* __restrict__ pair_cnt,
                  const float* __restrict__ np_sum, float* __restrict__ out)
{
    __shared__ float r1[256], r2[256];
    __shared__ int ri[256];
    const int t = threadIdx.x;
    float s1 = 0.f, s2 = 0.f; int c1 = 0;
    for (int i = t; i < Bn; i += 256) { s1 += pair_sum[i]; c1 += pair_cnt[i]; s2 += np_sum[i]; }
    r1[t] = s1; r2[t] = s2; ri[t] = c1;
    __syncthreads();
    for (int s = 128; s > 0; s >>= 1) {
        if (t < s) { r1[t] += r1[t + s]; r2[t] += r2[t + s]; ri[t] += ri[t + s]; }
        __syncthreads();
    }
    if (t == 0) {
        const int n = ri[0];
        out[0] = (n > 0) ? (r1[0] / (float)(n > 1 ? n : 1)) : 0.f;
        out[1] = r2[0] / (float)(Bn * 60);
    }
}

extern "C" void kernel_launch(void* const* d_in, const int* in_sizes, int n_in,
                              void* d_out, int out_size, void* d_ws, size_t ws_size,
                              hipStream_t stream)
{
    const float* hidden = (const float*)d_in[0];
    const int*   labels = (const int*)d_in[1];
    const float* W1 = (const float*)d_in[2];   const float* b1 = (const float*)d_in[3];
    const float* W2 = (const float*)d_in[4];   const float* b2 = (const float*)d_in[5];
    const float* W3 = (const float*)d_in[6];   const float* b3 = (const float*)d_in[7];
    const float* W4 = (const float*)d_in[8];   const float* b4 = (const float*)d_in[9];
    const float* W5 = (const float*)d_in[10];  const float* b5 = (const float*)d_in[11];
    const float* rW1 = (const float*)d_in[12]; const float* rb1 = (const float*)d_in[13];
    const float* rW2 = (const float*)d_in[14]; const float* rb2 = (const float*)d_in[15];
    const float* rW3 = (const float*)d_in[16]; const float* rb3 = (const float*)d_in[17];
    const float* rW4 = (const float*)d_in[18]; const float* rb4 = (const float*)d_in[19];
    const float* rW5 = (const float*)d_in[20]; const float* rb5 = (const float*)d_in[21];

    float* wsf      = (float*)d_ws;
    float* scoresb  = wsf;                         // [2][B][C]  (set0=cur, set1=ref)
    float* pair_sum = wsf + (size_t)2 * Bn * Cn;   // [B]
    float* np_sum   = pair_sum + Bn;               // [B]
    int*   pair_cnt = (int*)(np_sum + Bn);         // [B]
    float* out      = (float*)d_out;

    dim3 g1(Bn / TBr, Cn, 2);
    scores_kernel<<<g1, 256, 0, stream>>>(hidden,
        W1, b1, W2, b2, W3, b3, W4, b4, W5, b5,
        rW1, rb1, rW2, rb2, rW3, rb3, rW4, rb4, rW5, rb5,
        scoresb);
    loss_kernel<<<Bn, 128, 0, stream>>>(scoresb, labels, pair_sum, np_sum, pair_cnt);
    final_kernel<<<1, 256, 0, stream>>>(pair_sum, pair_cnt, np_sum, out);
}

// Round 2
// 2480.489 us; speedup vs baseline: 2.5312x; 2.5312x over previous
//
#include <hip/hip_runtime.h>
#include <math.h>

typedef __attribute__((ext_vector_type(8))) short short8;
typedef __attribute__((ext_vector_type(4))) float f32x4;

#define Bn   4096
#define Dn   768
#define Cn   80
#define H1   256
#define H2   64
#define H3   16
#define H4   4
#define BM   64      // batch rows per block
#define BK   64      // K-step for layer 1

// fp32 -> bf16 RTNE
__device__ inline ushort f2bf(float f) {
    union { float f; unsigned u; } v; v.f = f;
    unsigned r = v.u + 0x7fffu + ((v.u >> 16) & 1u);
    return (ushort)(r >> 16);
}
__device__ inline unsigned pack2(float a, float b) {
    return (unsigned)f2bf(a) | ((unsigned)f2bf(b) << 16);
}

// LDS: phases are sequenced by barriers; union keeps total at 40 KB.
union SmemU {
    struct { ushort A[BM * BK];  ushort Bt[H1 * BK]; } p1;   //  8KB + 32KB
    struct { ushort W2t[H2 * BK]; ushort x1[BM * H1]; } p2;  //  8KB + 32KB (same offsets)
    struct { float x2[BM][H2 + 2]; float W3s[H2][H3]; float x3[BM][H3 + 1]; float x4[BM][H4 + 1]; } p3;
};

__global__ __launch_bounds__(256)
void scores_mfma(const float* __restrict__ hidden,
                 const float* __restrict__ W1, const float* __restrict__ b1,
                 const float* __restrict__ W2, const float* __restrict__ b2,
                 const float* __restrict__ W3, const float* __restrict__ b3,
                 const float* __restrict__ W4, const float* __restrict__ b4,
                 const float* __restrict__ W5, const float* __restrict__ b5,
                 const float* __restrict__ rW1, const float* __restrict__ rb1,
                 const float* __restrict__ rW2, const float* __restrict__ rb2,
                 const float* __restrict__ rW3, const float* __restrict__ rb3,
                 const float* __restrict__ rW4, const float* __restrict__ rb4,
                 const float* __restrict__ rW5, const float* __restrict__ rb5,
                 float* __restrict__ scores)
{
    __shared__ SmemU sm;
    const int t = threadIdx.x;
    const int wave = t >> 6, lane = t & 63;
    const int lrow = lane & 15;            // row/col within 16x16 fragment
    const int lk   = (lane >> 4) << 3;     // k-element group 0,8,16,24 within K=32

    // bijective XCD swizzle (nwg = 10240, divisible by 8)
    const int nwg = (Bn / BM) * Cn * 2;
    const int cpx = nwg >> 3;
    const int wg  = (blockIdx.x & 7) * cpx + (blockIdx.x >> 3);
    const int set = wg / ((Bn / BM) * Cn);
    const int rem = wg % ((Bn / BM) * Cn);
    const int c   = rem / (Bn / BM);
    const int b0  = (rem % (Bn / BM)) * BM;

    const float* pW1 = set ? rW1 : W1;  const float* pb1 = set ? rb1 : b1;
    const float* pW2 = set ? rW2 : W2;  const float* pb2 = set ? rb2 : b2;
    const float* pW3 = set ? rW3 : W3;  const float* pb3 = set ? rb3 : b3;
    const float* pW4 = set ? rW4 : W4;  const float* pb4 = set ? rb4 : b4;
    const float* pW5 = set ? rW5 : W5;  const float* pb5 = set ? rb5 : b5;

    // ================= layer 1: x1 = relu(hidden @ W1 + b1)   M=64 N=256 K=768
    f32x4 acc[4][4];
    #pragma unroll
    for (int i = 0; i < 4; ++i)
        #pragma unroll
        for (int j = 0; j < 4; ++j)
            acc[i][j] = (f32x4){0.f, 0.f, 0.f, 0.f};

    const int arow = t >> 2;           // 0..63
    const int akq  = (t & 3) * 16;     // k offset 0,16,32,48

    for (int k0 = 0; k0 < Dn; k0 += BK) {
        // --- stage A tile [64 rows][64 k] bf16, XOR-swizzled, b128 writes
        {
            const float* src = hidden + (size_t)(b0 + arow) * Dn + k0 + akq;
            const float4 v0 = ((const float4*)src)[0];
            const float4 v1 = ((const float4*)src)[1];
            const float4 v2 = ((const float4*)src)[2];
            const float4 v3 = ((const float4*)src)[3];
            uint4 w0, w1;
            w0.x = pack2(v0.x, v0.y); w0.y = pack2(v0.z, v0.w);
            w0.z = pack2(v1.x, v1.y); w0.w = pack2(v1.z, v1.w);
            w1.x = pack2(v2.x, v2.y); w1.y = pack2(v2.z, v2.w);
            w1.z = pack2(v3.x, v3.y); w1.w = pack2(v3.z, v3.w);
            const int base = arow * 128 + akq * 2;
            const int swz  = (arow & 7) << 4;
            *(uint4*)((char*)sm.p1.A + ((base)      ^ swz)) = w0;
            *(uint4*)((char*)sm.p1.A + ((base + 16) ^ swz)) = w1;
        }
        // --- stage B^T tile [256 n][64 k] bf16 (transpose W1 chunk), b64 writes
        {
            const float* wbase = pW1 + ((size_t)c * Dn + k0) * H1;
            #pragma unroll
            for (int s = 0; s < 4; ++s) {
                const int idx = s * 256 + t;
                const int nq  = (idx & 63) * 4;
                const int kq  = (idx >> 6) * 4;
                float rr[4][4];
                #pragma unroll
                for (int i = 0; i < 4; ++i)
                    *(float4*)&rr[i][0] = *(const float4*)&wbase[(size_t)(kq + i) * H1 + nq];
                #pragma unroll
                for (int j = 0; j < 4; ++j) {
                    uint2 w;
                    w.x = pack2(rr[0][j], rr[1][j]);
                    w.y = pack2(rr[2][j], rr[3][j]);
                    const int n = nq + j;
                    *(uint2*)((char*)sm.p1.Bt + ((n * 128 + kq * 2) ^ ((n & 7) << 4))) = w;
                }
            }
        }
        __syncthreads();
        // --- MFMA: 2 k-substeps of 32
        #pragma unroll
        for (int ks = 0; ks < 2; ++ks) {
            const int kb = ks * 64 + lk * 2;   // byte offset within 128B row
            short8 a[4], b[4];
            #pragma unroll
            for (int mt = 0; mt < 4; ++mt) {
                const int row = mt * 16 + lrow;
                a[mt] = *(const short8*)((const char*)sm.p1.A + ((row * 128 + kb) ^ ((row & 7) << 4)));
            }
            #pragma unroll
            for (int nt = 0; nt < 4; ++nt) {
                const int col = wave * 64 + nt * 16 + lrow;
                b[nt] = *(const short8*)((const char*)sm.p1.Bt + ((col * 128 + kb) ^ ((col & 7) << 4)));
            }
            #pragma unroll
            for (int mt = 0; mt < 4; ++mt)
                #pragma unroll
                for (int nt = 0; nt < 4; ++nt)
                    acc[mt][nt] = __builtin_amdgcn_mfma_f32_16x16x32_bf16(a[mt], b[nt], acc[mt][nt], 0, 0, 0);
        }
        __syncthreads();
    }

    // epilogue: bias + relu, write x1 bf16 [64 rows][256 cols], swizzled
    {
        const int crow0 = (lane >> 4) * 4;
        float bias1[4];
        #pragma unroll
        for (int nt = 0; nt < 4; ++nt)
            bias1[nt] = pb1[(size_t)c * H1 + wave * 64 + nt * 16 + lrow];
        #pragma unroll
        for (int mt = 0; mt < 4; ++mt)
            #pragma unroll
            for (int nt = 0; nt < 4; ++nt)
                #pragma unroll
                for (int r = 0; r < 4; ++r) {
                    const int row = mt * 16 + crow0 + r;
                    const int col = wave * 64 + nt * 16 + lrow;
                    const float v = fmaxf(acc[mt][nt][r] + bias1[nt], 0.f);
                    *(ushort*)((char*)sm.p2.x1 + ((row * 512 + col * 2) ^ ((row & 7) << 4))) = f2bf(v);
                }
    }
    __syncthreads();

    // ================= layer 2: x2 = relu(x1 @ W2 + b2)   M=64 N=64 K=256
    f32x4 acc2[4];
    #pragma unroll
    for (int j = 0; j < 4; ++j) acc2[j] = (f32x4){0.f, 0.f, 0.f, 0.f};

    for (int kc = 0; kc < 4; ++kc) {
        // stage W2^T chunk [64 n][64 k] bf16
        {
            const int nq = (t & 15) * 4;
            const int kq = (t >> 4) * 4;
            const float* w2base = pW2 + ((size_t)c * H1 + kc * 64 + kq) * H2 + nq;
            float rr[4][4];
            #pragma unroll
            for (int i = 0; i < 4; ++i)
                *(float4*)&rr[i][0] = *(const float4*)&w2base[(size_t)i * H2];
            #pragma unroll
            for (int j = 0; j < 4; ++j) {
                uint2 w;
                w.x = pack2(rr[0][j], rr[1][j]);
                w.y = pack2(rr[2][j], rr[3][j]);
                const int n = nq + j;
                *(uint2*)((char*)sm.p2.W2t + ((n * 128 + kq * 2) ^ ((n & 7) << 4))) = w;
            }
        }
        __syncthreads();
        #pragma unroll
        for (int ks = 0; ks < 2; ++ks) {
            const int kel  = kc * 64 + ks * 32 + lk;    // k element in x1
            const int rowA = wave * 16 + lrow;
            const short8 a = *(const short8*)((const char*)sm.p2.x1 +
                              ((rowA * 512 + kel * 2) ^ ((rowA & 7) << 4)));
            const int kb2 = (ks * 32 + lk) * 2;
            #pragma unroll
            for (int nt = 0; nt < 4; ++nt) {
                const int col = nt * 16 + lrow;
                const short8 b = *(const short8*)((const char*)sm.p2.W2t +
                                  ((col * 128 + kb2) ^ ((col & 7) << 4)));
                acc2[nt] = __builtin_amdgcn_mfma_f32_16x16x32_bf16(a, b, acc2[nt], 0, 0, 0);
            }
        }
        __syncthreads();
    }

    // epilogue: bias + relu -> x2 fp32 [64][66]
    {
        const int crow0 = (lane >> 4) * 4;
        #pragma unroll
        for (int nt = 0; nt < 4; ++nt) {
            const int col = nt * 16 + lrow;
            const float bb = pb2[(size_t)c * H2 + col];
            #pragma unroll
            for (int r = 0; r < 4; ++r) {
                const int row = wave * 16 + crow0 + r;
                sm.p3.x2[row][col] = fmaxf(acc2[nt][r] + bb, 0.f);
            }
        }
    }
    // stage W3 (64x16 fp32) — disjoint region, before the barrier
    ((float4*)sm.p3.W3s)[t] = ((const float4*)(pW3 + (size_t)c * (H2 * H3)))[t];
    __syncthreads();

    // ================= layer 3: 64 -> 16
    {
        const int row = t >> 2, p = (t & 3) * 4;
        float a3[4];
        #pragma unroll
        for (int j = 0; j < 4; ++j) a3[j] = pb3[(size_t)c * H3 + p + j];
        for (int k = 0; k < H2; ++k) {
            const float xv = sm.p3.x2[row][k];
            #pragma unroll
            for (int j = 0; j < 4; ++j)
                a3[j] = fmaf(xv, sm.p3.W3s[k][p + j], a3[j]);
        }
        #pragma unroll
        for (int j = 0; j < 4; ++j) sm.p3.x3[row][p + j] = a3[j];
    }
    __syncthreads();
    // ================= layer 4: 16 -> 4
    {
        const int row = t >> 2, o = t & 3;
        float a4 = pb4[(size_t)c * H4 + o];
        const float* w4c = pW4 + (size_t)c * (H3 * H4);
        #pragma unroll
        for (int k = 0; k < H3; ++k)
            a4 = fmaf(fmaxf(sm.p3.x3[row][k], 0.f), w4c[k * H4 + o], a4);
        sm.p3.x4[row][o] = a4;
    }
    __syncthreads();
    // ================= layer 5: 4 -> 1 -> sigmoid
    if (t < BM) {
        float x5 = pb5[c];
        #pragma unroll
        for (int k = 0; k < H4; ++k)
            x5 = fmaf(fmaxf(sm.p3.x4[t][k], 0.f), pW5[(size_t)c * H4 + k], x5);
        scores[((size_t)set * Bn + b0 + t) * Cn + c] = 1.f / (1.f + expf(-x5));
    }
}

__device__ inline float bce_f(float p, float y) {
    p = fminf(fmaxf(p, 1e-8f), 1.0f - 1e-8f);
    return -(y * logf(p) + (1.f - y) * log1pf(-p));
}

// one block per batch row; lanes 0..79 own one class each
__global__ __launch_bounds__(128)
void loss_kernel(const float* __restrict__ scores, const int* __restrict__ labels,
                 float* __restrict__ pair_sum, float* __restrict__ np_sum,
                 int* __restrict__ pair_cnt)
{
    __shared__ float ss[Cn], lt[Cn];
    __shared__ int lab[Cn];
    __shared__ float redf[128], redn[128];
    __shared__ int redi[128];

    const int b = blockIdx.x, t = threadIdx.x;
    float np_local = 0.f, ps_local = 0.f;
    int pc_local = 0;

    if (t < Cn) {
        const float s  = scores[(size_t)b * Cn + t];
        const float sr = scores[(size_t)Bn * Cn + (size_t)b * Cn + t];
        const int l = labels[(size_t)b * Cn + t];
        ss[t] = s; lab[t] = l;
        lt[t] = logf(s / (sr + 1e-8f) + 1e-8f);
        if (t >= 20) {
            const float y = (float)l;
            np_local = fmaxf(bce_f(s, y) - bce_f(sr, y) - 0.1f, 0.f);
        }
    }
    __syncthreads();
    if (t < Cn && lab[t] == 0) {
        const float sj = ss[t], ltj = lt[t];
        #pragma unroll
        for (int i = 0; i < 20; ++i) {
            if (lab[i] == 1 && sj >= ss[i]) {
                const float z = -(lt[i] - ltj);
                ps_local += fmaxf(z, 0.f) + log1pf(expf(-fabsf(z)));
                pc_local++;
            }
        }
    }
    redf[t] = ps_local; redn[t] = np_local; redi[t] = pc_local;
    __syncthreads();
    for (int s = 64; s > 0; s >>= 1) {
        if (t < s) { redf[t] += redf[t + s]; redn[t] += redn[t + s]; redi[t] += redi[t + s]; }
        __syncthreads();
    }
    if (t == 0) { pair_sum[b] = redf[0]; np_sum[b] = redn[0]; pair_cnt[b] = redi[0]; }
}

__global__ __launch_bounds__(256)
void final_kernel(const float* __restrict__ pair_sum, const int* __restrict__ pair_cnt,
                  const float* __restrict__ np_sum, float* __restrict__ out)
{
    __shared__ float r1[256], r2[256];
    __shared__ int ri[256];
    const int t = threadIdx.x;
    float s1 = 0.f, s2 = 0.f; int c1 = 0;
    for (int i = t; i < Bn; i += 256) { s1 += pair_sum[i]; c1 += pair_cnt[i]; s2 += np_sum[i]; }
    r1[t] = s1; r2[t] = s2; ri[t] = c1;
    __syncthreads();
    for (int s = 128; s > 0; s >>= 1) {
        if (t < s) { r1[t] += r1[t + s]; r2[t] += r2[t + s]; ri[t] += ri[t + s]; }
        __syncthreads();
    }
    if (t == 0) {
        const int n = ri[0];
        out[0] = (n > 0) ? (r1[0] / (float)(n > 1 ? n : 1)) : 0.f;
        out[1] = r2[0] / (float)(Bn * 60);
    }
}

extern "C" void kernel_launch(void* const* d_in, const int* in_sizes, int n_in,
                              void* d_out, int out_size, void* d_ws, size_t ws_size,
                              hipStream_t stream)
{
    const float* hidden = (const float*)d_in[0];
    const int*   labels = (const int*)d_in[1];
    const float* W1 = (const float*)d_in[2];   const float* b1 = (const float*)d_in[3];
    const float* W2 = (const float*)d_in[4];   const float* b2 = (const float*)d_in[5];
    const float* W3 = (const float*)d_in[6];   const float* b3 = (const float*)d_in[7];
    const float* W4 = (const float*)d_in[8];   const float* b4 = (const float*)d_in[9];
    const float* W5 = (const float*)d_in[10];  const float* b5 = (const float*)d_in[11];
    const float* rW1 = (const float*)d_in[12]; const float* rb1 = (const float*)d_in[13];
    const float* rW2 = (const float*)d_in[14]; const float* rb2 = (const float*)d_in[15];
    const float* rW3 = (const float*)d_in[16]; const float* rb3 = (const float*)d_in[17];
    const float* rW4 = (const float*)d_in[18]; const float* rb4 = (const float*)d_in[19];
    const float* rW5 = (const float*)d_in[20]; const float* rb5 = (const float*)d_in[21];

    float* wsf      = (float*)d_ws;
    float* scoresb  = wsf;                         // [2][B][C]
    float* pair_sum = wsf + (size_t)2 * Bn * Cn;   // [B]
    float* np_sum   = pair_sum + Bn;               // [B]
    int*   pair_cnt = (int*)(np_sum + Bn);         // [B]
    float* out      = (float*)d_out;

    const int nwg = (Bn / BM) * Cn * 2;            // 10240
    scores_mfma<<<nwg, 256, 0, stream>>>(hidden,
        W1, b1, W2, b2, W3, b3, W4, b4, W5, b5,
        rW1, rb1, rW2, rb2, rW3, rb3, rW4, rb4, rW5, rb5,
        scoresb);
    loss_kernel<<<Bn, 128, 0, stream>>>(scoresb, labels, pair_sum, np_sum, pair_cnt);
    final_kernel<<<1, 256, 0, stream>>>(pair_sum, pair_cnt, np_sum, out);
}

// Round 3
// 591.304 us; speedup vs baseline: 10.6181x; 4.1949x over previous
//
#include <hip/hip_runtime.h>
#include <math.h>

typedef __attribute__((ext_vector_type(8))) short short8;
typedef __attribute__((ext_vector_type(4))) float f32x4;

#define Bn   4096
#define Dn   768
#define Cn   80
#define H1   256
#define H2   64
#define H3   16
#define H4   4
#define BM   64      // batch rows per block
#define BK   64      // K-step for layer 1

// fp32 -> bf16 RTNE
__device__ inline ushort f2bf(float f) {
    union { float f; unsigned u; } v; v.f = f;
    unsigned r = v.u + 0x7fffu + ((v.u >> 16) & 1u);
    return (ushort)(r >> 16);
}
__device__ inline unsigned pack2(float a, float b) {
    return (unsigned)f2bf(a) | ((unsigned)f2bf(b) << 16);
}

__device__ inline void load_lds16(const void* g, void* l) {
    __builtin_amdgcn_global_load_lds(
        (const __attribute__((address_space(1))) void*)g,
        (__attribute__((address_space(3))) void*)l, 16, 0, 0);
}

// ===================== Pass A: conversion kernels =====================
// hbs: per (b-tile, k-tile) 8KB tile; byte o in tile: row=o>>7, slot=(o>>4)&7,
// element k = kt*64 + (slot^(row&7))*8 + j  -> LDS after linear copy holds the
// XOR-swizzled tile: element k of row at byte (row*128 + 2k) ^ ((row&7)<<4).
__global__ __launch_bounds__(256)
void convert_hidden(const float* __restrict__ hidden, ushort* __restrict__ hbs)
{
    const int t = threadIdx.x;
    const int kt = blockIdx.x;           // 0..11
    const int bt = blockIdx.y;           // 0..63
    char* out = (char*)(hbs + ((size_t)bt * 12 + kt) * 4096);
    #pragma unroll
    for (int ch = 0; ch < 2; ++ch) {
        const int o = (ch * 256 + t) * 16;
        const int row = o >> 7;
        const int slot = (o >> 4) & 7;
        const int ss = slot ^ (row & 7);
        const float* src = hidden + (size_t)(bt * 64 + row) * Dn + kt * 64 + ss * 8;
        const float4 f0 = ((const float4*)src)[0];
        const float4 f1 = ((const float4*)src)[1];
        uint4 w;
        w.x = pack2(f0.x, f0.y); w.y = pack2(f0.z, f0.w);
        w.z = pack2(f1.x, f1.y); w.w = pack2(f1.z, f1.w);
        *(uint4*)(out + o) = w;
    }
}

// W (C,Ktot,N) -> tiles [set][c][k0t] of N x 64k bf16, pre-swizzled, transposed.
// tile byte o: n=o>>7, slot=(o>>4)&7, k elements = k0t*64 + (slot^(n&7))*8 + j.
__global__ __launch_bounds__(256)
void convert_w(const float* __restrict__ W, const float* __restrict__ rW,
               ushort* __restrict__ dst, int Ktot, int N)
{
    extern __shared__ float lds[];       // [64][N]
    const int t = threadIdx.x;
    const int k0t = blockIdx.x;
    const int c   = blockIdx.y;
    const int set = blockIdx.z;
    const float* src = (set ? rW : W) + ((size_t)c * Ktot + k0t * 64) * N;
    const int nf4 = 64 * N / 4;
    for (int i = t; i < nf4; i += 256)
        ((float4*)lds)[i] = ((const float4*)src)[i];
    __syncthreads();
    char* out = (char*)(dst + (((size_t)set * Cn + c) * gridDim.x + k0t) * (size_t)(N * 64));
    const int nch = N / 32;              // chunks of 16B per thread
    for (int ch = 0; ch < nch; ++ch) {
        const int o = (ch * 256 + t) * 16;
        const int n = o >> 7;
        const int slot = (o >> 4) & 7;
        const int kl = (slot ^ (n & 7)) * 8;
        uint4 w;
        w.x = pack2(lds[(kl + 0) * N + n], lds[(kl + 1) * N + n]);
        w.y = pack2(lds[(kl + 2) * N + n], lds[(kl + 3) * N + n]);
        w.z = pack2(lds[(kl + 4) * N + n], lds[(kl + 5) * N + n]);
        w.w = pack2(lds[(kl + 6) * N + n], lds[(kl + 7) * N + n]);
        *(uint4*)(out + o) = w;
    }
}

// ===================== Pass B: fused MFMA scores kernel =====================
union SmemU {
    struct { ushort A[BM * BK];  ushort Bt[H1 * BK]; } p1;   //  8KB + 32KB
    struct { ushort W2t[H2 * BK]; ushort x1[BM * H1]; } p2;  //  8KB + 32KB
    struct { float x2[BM][H2 + 2]; float W3s[H2][H3]; float x3[BM][H3 + 1]; float x4[BM][H4 + 1]; } p3;
};

__global__ __launch_bounds__(256)
void scores_mfma_fast(const ushort* __restrict__ hbs, const ushort* __restrict__ W1ts,
                      const ushort* __restrict__ W2ts,
                      const float* __restrict__ b1, const float* __restrict__ rb1,
                      const float* __restrict__ b2, const float* __restrict__ rb2,
                      const float* __restrict__ W3, const float* __restrict__ rW3,
                      const float* __restrict__ b3, const float* __restrict__ rb3,
                      const float* __restrict__ W4, const float* __restrict__ rW4,
                      const float* __restrict__ b4, const float* __restrict__ rb4,
                      const float* __restrict__ W5, const float* __restrict__ rW5,
                      const float* __restrict__ b5, const float* __restrict__ rb5,
                      float* __restrict__ scores)
{
    __shared__ SmemU sm;
    const int t = threadIdx.x;
    const int wave = t >> 6, lane = t & 63;
    const int lrow = lane & 15;
    const int lk   = (lane >> 4) << 3;

    const int nwg = (Bn / BM) * Cn * 2;
    const int cpx = nwg >> 3;
    const int wg  = (blockIdx.x & 7) * cpx + (blockIdx.x >> 3);
    const int set = wg / ((Bn / BM) * Cn);
    const int rem = wg % ((Bn / BM) * Cn);
    const int c   = rem / (Bn / BM);
    const int b0  = (rem % (Bn / BM)) * BM;

    const float* pb1 = set ? rb1 : b1;
    const float* pb2 = set ? rb2 : b2;
    const float* pW3 = set ? rW3 : W3;  const float* pb3 = set ? rb3 : b3;
    const float* pW4 = set ? rW4 : W4;  const float* pb4 = set ? rb4 : b4;
    const float* pW5 = set ? rW5 : W5;  const float* pb5 = set ? rb5 : b5;

    // ---------- layer 1: M=64 N=256 K=768
    f32x4 acc[4][4];
    #pragma unroll
    for (int i = 0; i < 4; ++i)
        #pragma unroll
        for (int j = 0; j < 4; ++j)
            acc[i][j] = (f32x4){0.f, 0.f, 0.f, 0.f};

    const char* srcA = (const char*)(hbs + ((size_t)(b0 >> 6) * 12) * 4096);
    const char* srcB = (const char*)(W1ts + ((size_t)(set * Cn + c) * 12) * 16384);
    char* ldsA = (char*)sm.p1.A;
    char* ldsB = (char*)sm.p1.Bt;

    for (int k0t = 0; k0t < 12; ++k0t) {
        {   // A: 8KB, 2 issues/wave; Bt: 32KB, 8 issues/wave (linear dest)
            const char* gA = srcA + k0t * 8192 + wave * 2048 + lane * 16;
            char* lA = ldsA + wave * 2048;
            load_lds16(gA,        lA);
            load_lds16(gA + 1024, lA + 1024);
            const char* gB = srcB + k0t * 32768 + wave * 8192 + lane * 16;
            char* lB = ldsB + wave * 8192;
            #pragma unroll
            for (int i = 0; i < 8; ++i)
                load_lds16(gB + i * 1024, lB + i * 1024);
        }
        __syncthreads();
        #pragma unroll
        for (int ks = 0; ks < 2; ++ks) {
            const int kb = ks * 64 + lk * 2;
            short8 a[4], b[4];
            #pragma unroll
            for (int mt = 0; mt < 4; ++mt) {
                const int row = mt * 16 + lrow;
                a[mt] = *(const short8*)(ldsA + ((row * 128 + kb) ^ ((row & 7) << 4)));
            }
            #pragma unroll
            for (int nt = 0; nt < 4; ++nt) {
                const int col = wave * 64 + nt * 16 + lrow;
                b[nt] = *(const short8*)(ldsB + ((col * 128 + kb) ^ ((col & 7) << 4)));
            }
            #pragma unroll
            for (int mt = 0; mt < 4; ++mt)
                #pragma unroll
                for (int nt = 0; nt < 4; ++nt)
                    acc[mt][nt] = __builtin_amdgcn_mfma_f32_16x16x32_bf16(a[mt], b[nt], acc[mt][nt], 0, 0, 0);
        }
        __syncthreads();
    }

    // epilogue: bias + relu -> x1 bf16 swizzled
    {
        const int crow0 = (lane >> 4) * 4;
        float bias1[4];
        #pragma unroll
        for (int nt = 0; nt < 4; ++nt)
            bias1[nt] = pb1[(size_t)c * H1 + wave * 64 + nt * 16 + lrow];
        #pragma unroll
        for (int mt = 0; mt < 4; ++mt)
            #pragma unroll
            for (int nt = 0; nt < 4; ++nt)
                #pragma unroll
                for (int r = 0; r < 4; ++r) {
                    const int row = mt * 16 + crow0 + r;
                    const int col = wave * 64 + nt * 16 + lrow;
                    const float v = fmaxf(acc[mt][nt][r] + bias1[nt], 0.f);
                    *(ushort*)((char*)sm.p2.x1 + ((row * 512 + col * 2) ^ ((row & 7) << 4))) = f2bf(v);
                }
    }
    __syncthreads();

    // ---------- layer 2: M=64 N=64 K=256
    f32x4 acc2[4];
    #pragma unroll
    for (int j = 0; j < 4; ++j) acc2[j] = (f32x4){0.f, 0.f, 0.f, 0.f};

    const char* srcW2 = (const char*)(W2ts + ((size_t)(set * Cn + c) * 4) * 4096);
    char* ldsW2 = (char*)sm.p2.W2t;

    for (int kc = 0; kc < 4; ++kc) {
        {   // 8KB chunk, 2 issues/wave
            const char* g = srcW2 + kc * 8192 + wave * 2048 + lane * 16;
            char* l = ldsW2 + wave * 2048;
            load_lds16(g,        l);
            load_lds16(g + 1024, l + 1024);
        }
        __syncthreads();
        #pragma unroll
        for (int ks = 0; ks < 2; ++ks) {
            const int kel  = kc * 64 + ks * 32 + lk;
            const int rowA = wave * 16 + lrow;
            const short8 a = *(const short8*)((const char*)sm.p2.x1 +
                              ((rowA * 512 + kel * 2) ^ ((rowA & 7) << 4)));
            const int kb2 = (ks * 32 + lk) * 2;
            #pragma unroll
            for (int nt = 0; nt < 4; ++nt) {
                const int col = nt * 16 + lrow;
                const short8 b = *(const short8*)(ldsW2 + ((col * 128 + kb2) ^ ((col & 7) << 4)));
                acc2[nt] = __builtin_amdgcn_mfma_f32_16x16x32_bf16(a, b, acc2[nt], 0, 0, 0);
            }
        }
        __syncthreads();
    }

    // epilogue: bias + relu -> x2 fp32
    {
        const int crow0 = (lane >> 4) * 4;
        #pragma unroll
        for (int nt = 0; nt < 4; ++nt) {
            const int col = nt * 16 + lrow;
            const float bb = pb2[(size_t)c * H2 + col];
            #pragma unroll
            for (int r = 0; r < 4; ++r) {
                const int row = wave * 16 + crow0 + r;
                sm.p3.x2[row][col] = fmaxf(acc2[nt][r] + bb, 0.f);
            }
        }
    }
    ((float4*)sm.p3.W3s)[t] = ((const float4*)(pW3 + (size_t)c * (H2 * H3)))[t];
    __syncthreads();

    // ---------- layer 3: 64 -> 16
    {
        const int row = t >> 2, p = (t & 3) * 4;
        float a3[4];
        #pragma unroll
        for (int j = 0; j < 4; ++j) a3[j] = pb3[(size_t)c * H3 + p + j];
        for (int k = 0; k < H2; ++k) {
            const float xv = sm.p3.x2[row][k];
            #pragma unroll
            for (int j = 0; j < 4; ++j)
                a3[j] = fmaf(xv, sm.p3.W3s[k][p + j], a3[j]);
        }
        #pragma unroll
        for (int j = 0; j < 4; ++j) sm.p3.x3[row][p + j] = a3[j];
    }
    __syncthreads();
    // ---------- layer 4: 16 -> 4
    {
        const int row = t >> 2, o = t & 3;
        float a4 = pb4[(size_t)c * H4 + o];
        const float* w4c = pW4 + (size_t)c * (H3 * H4);
        #pragma unroll
        for (int k = 0; k < H3; ++k)
            a4 = fmaf(fmaxf(sm.p3.x3[row][k], 0.f), w4c[k * H4 + o], a4);
        sm.p3.x4[row][o] = a4;
    }
    __syncthreads();
    // ---------- layer 5: 4 -> 1 -> sigmoid
    if (t < BM) {
        float x5 = pb5[c];
        #pragma unroll
        for (int k = 0; k < H4; ++k)
            x5 = fmaf(fmaxf(sm.p3.x4[t][k], 0.f), pW5[(size_t)c * H4 + k], x5);
        scores[((size_t)set * Bn + b0 + t) * Cn + c] = 1.f / (1.f + expf(-x5));
    }
}

// ===================== Fallback (R2 kernel, used only if ws too small) =====================
__global__ __launch_bounds__(256)
void scores_mfma(const float* __restrict__ hidden,
                 const float* __restrict__ W1, const float* __restrict__ b1,
                 const float* __restrict__ W2, const float* __restrict__ b2,
                 const float* __restrict__ W3, const float* __restrict__ b3,
                 const float* __restrict__ W4, const float* __restrict__ b4,
                 const float* __restrict__ W5, const float* __restrict__ b5,
                 const float* __restrict__ rW1, const float* __restrict__ rb1,
                 const float* __restrict__ rW2, const float* __restrict__ rb2,
                 const float* __restrict__ rW3, const float* __restrict__ rb3,
                 const float* __restrict__ rW4, const float* __restrict__ rb4,
                 const float* __restrict__ rW5, const float* __restrict__ rb5,
                 float* __restrict__ scores)
{
    __shared__ SmemU sm;
    const int t = threadIdx.x;
    const int wave = t >> 6, lane = t & 63;
    const int lrow = lane & 15;
    const int lk   = (lane >> 4) << 3;

    const int nwg = (Bn / BM) * Cn * 2;
    const int cpx = nwg >> 3;
    const int wg  = (blockIdx.x & 7) * cpx + (blockIdx.x >> 3);
    const int set = wg / ((Bn / BM) * Cn);
    const int rem = wg % ((Bn / BM) * Cn);
    const int c   = rem / (Bn / BM);
    const int b0  = (rem % (Bn / BM)) * BM;

    const float* pW1 = set ? rW1 : W1;  const float* pb1 = set ? rb1 : b1;
    const float* pW2 = set ? rW2 : W2;  const float* pb2 = set ? rb2 : b2;
    const float* pW3 = set ? rW3 : W3;  const float* pb3 = set ? rb3 : b3;
    const float* pW4 = set ? rW4 : W4;  const float* pb4 = set ? rb4 : b4;
    const float* pW5 = set ? rW5 : W5;  const float* pb5 = set ? rb5 : b5;

    f32x4 acc[4][4];
    #pragma unroll
    for (int i = 0; i < 4; ++i)
        #pragma unroll
        for (int j = 0; j < 4; ++j)
            acc[i][j] = (f32x4){0.f, 0.f, 0.f, 0.f};

    const int arow = t >> 2;
    const int akq  = (t & 3) * 16;

    for (int k0 = 0; k0 < Dn; k0 += BK) {
        {
            const float* src = hidden + (size_t)(b0 + arow) * Dn + k0 + akq;
            const float4 v0 = ((const float4*)src)[0];
            const float4 v1 = ((const float4*)src)[1];
            const float4 v2 = ((const float4*)src)[2];
            const float4 v3 = ((const float4*)src)[3];
            uint4 w0, w1;
            w0.x = pack2(v0.x, v0.y); w0.y = pack2(v0.z, v0.w);
            w0.z = pack2(v1.x, v1.y); w0.w = pack2(v1.z, v1.w);
            w1.x = pack2(v2.x, v2.y); w1.y = pack2(v2.z, v2.w);
            w1.z = pack2(v3.x, v3.y); w1.w = pack2(v3.z, v3.w);
            const int base = arow * 128 + akq * 2;
            const int swz  = (arow & 7) << 4;
            *(uint4*)((char*)sm.p1.A + ((base)      ^ swz)) = w0;
            *(uint4*)((char*)sm.p1.A + ((base + 16) ^ swz)) = w1;
        }
        {
            const float* wbase = pW1 + ((size_t)c * Dn + k0) * H1;
            #pragma unroll
            for (int s = 0; s < 4; ++s) {
                const int idx = s * 256 + t;
                const int nq  = (idx & 63) * 4;
                const int kq  = (idx >> 6) * 4;
                float rr[4][4];
                #pragma unroll
                for (int i = 0; i < 4; ++i)
                    *(float4*)&rr[i][0] = *(const float4*)&wbase[(size_t)(kq + i) * H1 + nq];
                #pragma unroll
                for (int j = 0; j < 4; ++j) {
                    uint2 w;
                    w.x = pack2(rr[0][j], rr[1][j]);
                    w.y = pack2(rr[2][j], rr[3][j]);
                    const int n = nq + j;
                    *(uint2*)((char*)sm.p1.Bt + ((n * 128 + kq * 2) ^ ((n & 7) << 4))) = w;
                }
            }
        }
        __syncthreads();
        #pragma unroll
        for (int ks = 0; ks < 2; ++ks) {
            const int kb = ks * 64 + lk * 2;
            short8 a[4], b[4];
            #pragma unroll
            for (int mt = 0; mt < 4; ++mt) {
                const int row = mt * 16 + lrow;
                a[mt] = *(const short8*)((const char*)sm.p1.A + ((row * 128 + kb) ^ ((row & 7) << 4)));
            }
            #pragma unroll
            for (int nt = 0; nt < 4; ++nt) {
                const int col = wave * 64 + nt * 16 + lrow;
                b[nt] = *(const short8*)((const char*)sm.p1.Bt + ((col * 128 + kb) ^ ((col & 7) << 4)));
            }
            #pragma unroll
            for (int mt = 0; mt < 4; ++mt)
                #pragma unroll
                for (int nt = 0; nt < 4; ++nt)
                    acc[mt][nt] = __builtin_amdgcn_mfma_f32_16x16x32_bf16(a[mt], b[nt], acc[mt][nt], 0, 0, 0);
        }
        __syncthreads();
    }

    {
        const int crow0 = (lane >> 4) * 4;
        float bias1[4];
        #pragma unroll
        for (int nt = 0; nt < 4; ++nt)
            bias1[nt] = pb1[(size_t)c * H1 + wave * 64 + nt * 16 + lrow];
        #pragma unroll
        for (int mt = 0; mt < 4; ++mt)
            #pragma unroll
            for (int nt = 0; nt < 4; ++nt)
                #pragma unroll
                for (int r = 0; r < 4; ++r) {
                    const int row = mt * 16 + crow0 + r;
                    const int col = wave * 64 + nt * 16 + lrow;
                    const float v = fmaxf(acc[mt][nt][r] + bias1[nt], 0.f);
                    *(ushort*)((char*)sm.p2.x1 + ((row * 512 + col * 2) ^ ((row & 7) << 4))) = f2bf(v);
                }
    }
    __syncthreads();

    f32x4 acc2[4];
    #pragma unroll
    for (int j = 0; j < 4; ++j) acc2[j] = (f32x4){0.f, 0.f, 0.f, 0.f};

    for (int kc = 0; kc < 4; ++kc) {
        {
            const int nq = (t & 15) * 4;
            const int kq = (t >> 4) * 4;
            const float* w2base = pW2 + ((size_t)c * H1 + kc * 64 + kq) * H2 + nq;
            float rr[4][4];
            #pragma unroll
            for (int i = 0; i < 4; ++i)
                *(float4*)&rr[i][0] = *(const float4*)&w2base[(size_t)i * H2];
            #pragma unroll
            for (int j = 0; j < 4; ++j) {
                uint2 w;
                w.x = pack2(rr[0][j], rr[1][j]);
                w.y = pack2(rr[2][j], rr[3][j]);
                const int n = nq + j;
                *(uint2*)((char*)sm.p2.W2t + ((n * 128 + kq * 2) ^ ((n & 7) << 4))) = w;
            }
        }
        __syncthreads();
        #pragma unroll
        for (int ks = 0; ks < 2; ++ks) {
            const int kel  = kc * 64 + ks * 32 + lk;
            const int rowA = wave * 16 + lrow;
            const short8 a = *(const short8*)((const char*)sm.p2.x1 +
                              ((rowA * 512 + kel * 2) ^ ((rowA & 7) << 4)));
            const int kb2 = (ks * 32 + lk) * 2;
            #pragma unroll
            for (int nt = 0; nt < 4; ++nt) {
                const int col = nt * 16 + lrow;
                const short8 b = *(const short8*)((const char*)sm.p2.W2t +
                                  ((col * 128 + kb2) ^ ((col & 7) << 4)));
                acc2[nt] = __builtin_amdgcn_mfma_f32_16x16x32_bf16(a, b, acc2[nt], 0, 0, 0);
            }
        }
        __syncthreads();
    }

    {
        const int crow0 = (lane >> 4) * 4;
        #pragma unroll
        for (int nt = 0; nt < 4; ++nt) {
            const int col = nt * 16 + lrow;
            const float bb = pb2[(size_t)c * H2 + col];
            #pragma unroll
            for (int r = 0; r < 4; ++r) {
                const int row = wave * 16 + crow0 + r;
                sm.p3.x2[row][col] = fmaxf(acc2[nt][r] + bb, 0.f);
            }
        }
    }
    ((float4*)sm.p3.W3s)[t] = ((const float4*)(pW3 + (size_t)c * (H2 * H3)))[t];
    __syncthreads();

    {
        const int row = t >> 2, p = (t & 3) * 4;
        float a3[4];
        #pragma unroll
        for (int j = 0; j < 4; ++j) a3[j] = pb3[(size_t)c * H3 + p + j];
        for (int k = 0; k < H2; ++k) {
            const float xv = sm.p3.x2[row][k];
            #pragma unroll
            for (int j = 0; j < 4; ++j)
                a3[j] = fmaf(xv, sm.p3.W3s[k][p + j], a3[j]);
        }
        #pragma unroll
        for (int j = 0; j < 4; ++j) sm.p3.x3[row][p + j] = a3[j];
    }
    __syncthreads();
    {
        const int row = t >> 2, o = t & 3;
        float a4 = pb4[(size_t)c * H4 + o];
        const float* w4c = pW4 + (size_t)c * (H3 * H4);
        #pragma unroll
        for (int k = 0; k < H3; ++k)
            a4 = fmaf(fmaxf(sm.p3.x3[row][k], 0.f), w4c[k * H4 + o], a4);
        sm.p3.x4[row][o] = a4;
    }
    __syncthreads();
    if (t < BM) {
        float x5 = pb5[c];
        #pragma unroll
        for (int k = 0; k < H4; ++k)
            x5 = fmaf(fmaxf(sm.p3.x4[t][k], 0.f), pW5[(size_t)c * H4 + k], x5);
        scores[((size_t)set * Bn + b0 + t) * Cn + c] = 1.f / (1.f + expf(-x5));
    }
}

// ===================== loss kernels =====================
__device__ inline float bce_f(float p, float y) {
    p = fminf(fmaxf(p, 1e-8f), 1.0f - 1e-8f);
    return -(y * logf(p) + (1.f - y) * log1pf(-p));
}

__global__ __launch_bounds__(128)
void loss_kernel(const float* __restrict__ scores, const int* __restrict__ labels,
                 float* __restrict__ pair_sum, float* __restrict__ np_sum,
                 int* __restrict__ pair_cnt)
{
    __shared__ float ss[Cn], lt[Cn];
    __shared__ int lab[Cn];
    __shared__ float redf[128], redn[128];
    __shared__ int redi[128];

    const int b = blockIdx.x, t = threadIdx.x;
    float np_local = 0.f, ps_local = 0.f;
    int pc_local = 0;

    if (t < Cn) {
        const float s  = scores[(size_t)b * Cn + t];
        const float sr = scores[(size_t)Bn * Cn + (size_t)b * Cn + t];
        const int l = labels[(size_t)b * Cn + t];
        ss[t] = s; lab[t] = l;
        lt[t] = logf(s / (sr + 1e-8f) + 1e-8f);
        if (t >= 20) {
            const float y = (float)l;
            np_local = fmaxf(bce_f(s, y) - bce_f(sr, y) - 0.1f, 0.f);
        }
    }
    __syncthreads();
    if (t < Cn && lab[t] == 0) {
        const float sj = ss[t], ltj = lt[t];
        #pragma unroll
        for (int i = 0; i < 20; ++i) {
            if (lab[i] == 1 && sj >= ss[i]) {
                const float z = -(lt[i] - ltj);
                ps_local += fmaxf(z, 0.f) + log1pf(expf(-fabsf(z)));
                pc_local++;
            }
        }
    }
    redf[t] = ps_local; redn[t] = np_local; redi[t] = pc_local;
    __syncthreads();
    for (int s = 64; s > 0; s >>= 1) {
        if (t < s) { redf[t] += redf[t + s]; redn[t] += redn[t + s]; redi[t] += redi[t + s]; }
        __syncthreads();
    }
    if (t == 0) { pair_sum[b] = redf[0]; np_sum[b] = redn[0]; pair_cnt[b] = redi[0]; }
}

__global__ __launch_bounds__(256)
void final_kernel(const float* __restrict__ pair_sum, const int* __restrict__ pair_cnt,
                  const float* __restrict__ np_sum, float* __restrict__ out)
{
    __shared__ float r1[256], r2[256];
    __shared__ int ri[256];
    const int t = threadIdx.x;
    float s1 = 0.f, s2 = 0.f; int c1 = 0;
    for (int i = t; i < Bn; i += 256) { s1 += pair_sum[i]; c1 += pair_cnt[i]; s2 += np_sum[i]; }
    r1[t] = s1; r2[t] = s2; ri[t] = c1;
    __syncthreads();
    for (int s = 128; s > 0; s >>= 1) {
        if (t < s) { r1[t] += r1[t + s]; r2[t] += r2[t + s]; ri[t] += ri[t + s]; }
        __syncthreads();
    }
    if (t == 0) {
        const int n = ri[0];
        out[0] = (n > 0) ? (r1[0] / (float)(n > 1 ? n : 1)) : 0.f;
        out[1] = r2[0] / (float)(Bn * 60);
    }
}

// ===================== launch =====================
static inline size_t alup(size_t x) { return (x + 4095) & ~(size_t)4095; }

extern "C" void kernel_launch(void* const* d_in, const int* in_sizes, int n_in,
                              void* d_out, int out_size, void* d_ws, size_t ws_size,
                              hipStream_t stream)
{
    const float* hidden = (const float*)d_in[0];
    const int*   labels = (const int*)d_in[1];
    const float* W1 = (const float*)d_in[2];   const float* b1 = (const float*)d_in[3];
    const float* W2 = (const float*)d_in[4];   const float* b2 = (const float*)d_in[5];
    const float* W3 = (const float*)d_in[6];   const float* b3 = (const float*)d_in[7];
    const float* W4 = (const float*)d_in[8];   const float* b4 = (const float*)d_in[9];
    const float* W5 = (const float*)d_in[10];  const float* b5 = (const float*)d_in[11];
    const float* rW1 = (const float*)d_in[12]; const float* rb1 = (const float*)d_in[13];
    const float* rW2 = (const float*)d_in[14]; const float* rb2 = (const float*)d_in[15];
    const float* rW3 = (const float*)d_in[16]; const float* rb3 = (const float*)d_in[17];
    const float* rW4 = (const float*)d_in[18]; const float* rb4 = (const float*)d_in[19];
    const float* rW5 = (const float*)d_in[20]; const float* rb5 = (const float*)d_in[21];

    char* ws = (char*)d_ws;
    const size_t off_scores = 0;
    const size_t sz_scores  = (size_t)2 * Bn * Cn * 4;
    const size_t off_pair   = alup(off_scores + sz_scores);
    const size_t sz_pair    = (size_t)3 * Bn * 4;
    const size_t off_hbs    = alup(off_pair + sz_pair);
    const size_t sz_hbs     = (size_t)Bn * Dn * 2;
    const size_t off_w1t    = alup(off_hbs + sz_hbs);
    const size_t sz_w1t     = (size_t)2 * Cn * 12 * 16384 * 2;
    const size_t off_w2t    = alup(off_w1t + sz_w1t);
    const size_t sz_w2t     = (size_t)2 * Cn * 4 * 4096 * 2;
    const size_t need       = alup(off_w2t + sz_w2t);

    float* scoresb  = (float*)(ws + off_scores);
    float* pair_sum = (float*)(ws + off_pair);
    float* np_sum   = pair_sum + Bn;
    int*   pair_cnt = (int*)(np_sum + Bn);
    float* out      = (float*)d_out;

    const int nwg = (Bn / BM) * Cn * 2;            // 10240

    if (ws_size >= need) {
        ushort* hbs  = (ushort*)(ws + off_hbs);
        ushort* W1ts = (ushort*)(ws + off_w1t);
        ushort* W2ts = (ushort*)(ws + off_w2t);

        convert_hidden<<<dim3(12, Bn / 64), 256, 0, stream>>>(hidden, hbs);
        convert_w<<<dim3(12, Cn, 2), 256, 64 * H1 * 4, stream>>>(W1, rW1, W1ts, Dn, H1);
        convert_w<<<dim3(4,  Cn, 2), 256, 64 * H2 * 4, stream>>>(W2, rW2, W2ts, H1, H2);

        scores_mfma_fast<<<nwg, 256, 0, stream>>>(hbs, W1ts, W2ts,
            b1, rb1, b2, rb2, W3, rW3, b3, rb3, W4, rW4, b4, rb4, W5, rW5, b5, rb5,
            scoresb);
    } else {
        scores_mfma<<<nwg, 256, 0, stream>>>(hidden,
            W1, b1, W2, b2, W3, b3, W4, b4, W5, b5,
            rW1, rb1, rW2, rb2, rW3, rb3, rW4, rb4, rW5, rb5,
            scoresb);
    }
    loss_kernel<<<Bn, 128, 0, stream>>>(scoresb, labels, pair_sum, np_sum, pair_cnt);
    final_kernel<<<1, 256, 0, stream>>>(pair_sum, pair_cnt, np_sum, out);
}

// Round 4
// 405.209 us; speedup vs baseline: 15.4945x; 1.4593x over previous
//
#include <hip/hip_runtime.h>
#include <math.h>

typedef __attribute__((ext_vector_type(8))) short short8;
typedef __attribute__((ext_vector_type(4))) float f32x4;

#define Bn   4096
#define Dn   768
#define Cn   80
#define H1   256
#define H2   64
#define H3   16
#define H4   4

// fp32 -> bf16 RTNE
__device__ inline ushort f2bf(float f) {
    union { float f; unsigned u; } v; v.f = f;
    unsigned r = v.u + 0x7fffu + ((v.u >> 16) & 1u);
    return (ushort)(r >> 16);
}
__device__ inline unsigned pack2(float a, float b) {
    return (unsigned)f2bf(a) | ((unsigned)f2bf(b) << 16);
}
__device__ inline void load_lds16(const void* g, void* l) {
    __builtin_amdgcn_global_load_lds(
        (const __attribute__((address_space(1))) void*)g,
        (__attribute__((address_space(3))) void*)l, 16, 0, 0);
}

#define FENCE() asm volatile("" ::: "memory")
#define BAR() do { FENCE(); __builtin_amdgcn_sched_barrier(0); \
                   __builtin_amdgcn_s_barrier(); \
                   __builtin_amdgcn_sched_barrier(0); FENCE(); } while (0)
#define VMCNT4() do { asm volatile("s_waitcnt vmcnt(4)" ::: "memory"); \
                      __builtin_amdgcn_sched_barrier(0); } while (0)
#define VMCNT0() do { asm volatile("s_waitcnt vmcnt(0)" ::: "memory"); \
                      __builtin_amdgcn_sched_barrier(0); } while (0)

// ===================== Pass A: conversion kernels =====================
// hbs: per (b-tile64, k-tile64) 8KB tile, XOR-swizzled:
//   element (row r<64, k<64) at byte (r*128 + 2k) ^ ((r&7)<<4)
__global__ __launch_bounds__(256)
void convert_hidden(const float* __restrict__ hidden, ushort* __restrict__ hbs)
{
    const int t = threadIdx.x;
    const int kt = blockIdx.x;           // 0..11
    const int bt = blockIdx.y;           // 0..63
    char* out = (char*)(hbs + ((size_t)bt * 12 + kt) * 4096);
    #pragma unroll
    for (int ch = 0; ch < 2; ++ch) {
        const int o = (ch * 256 + t) * 16;
        const int row = o >> 7;
        const int slot = (o >> 4) & 7;
        const int ss = slot ^ (row & 7);
        const float* src = hidden + (size_t)(bt * 64 + row) * Dn + kt * 64 + ss * 8;
        const float4 f0 = ((const float4*)src)[0];
        const float4 f1 = ((const float4*)src)[1];
        uint4 w;
        w.x = pack2(f0.x, f0.y); w.y = pack2(f0.z, f0.w);
        w.z = pack2(f1.x, f1.y); w.w = pack2(f1.z, f1.w);
        *(uint4*)(out + o) = w;
    }
}

// W1 -> [set][c][kt*2+kh] tiles of 256n x 32k bf16, transposed & swizzled:
//   element (n<256, kk<32) at byte n*64 + (2kk ^ ((n&3)<<4))
__global__ __launch_bounds__(256)
void convert_w1(const float* __restrict__ W, const float* __restrict__ rW,
                ushort* __restrict__ dst)
{
    __shared__ float l[32 * H1];         // 32KB
    const int t   = threadIdx.x;
    const int kt2 = blockIdx.x;          // 0..23 (kt*2+kh)
    const int c   = blockIdx.y;
    const int set = blockIdx.z;
    const float* src = (set ? rW : W) + ((size_t)c * Dn + kt2 * 32) * H1;
    #pragma unroll
    for (int i = 0; i < 8; ++i)
        ((float4*)l)[i * 256 + t] = ((const float4*)src)[i * 256 + t];
    __syncthreads();
    char* out = (char*)dst + (((size_t)set * Cn + c) * 24 + kt2) * 16384;
    #pragma unroll
    for (int rd = 0; rd < 4; ++rd) {
        const int o = (rd * 256 + t) * 16;
        const int n = o >> 6;
        const int s = (o >> 4) & 3;
        const int kk0 = (s ^ (n & 3)) * 8;
        uint4 w;
        w.x = pack2(l[(kk0 + 0) * H1 + n], l[(kk0 + 1) * H1 + n]);
        w.y = pack2(l[(kk0 + 2) * H1 + n], l[(kk0 + 3) * H1 + n]);
        w.z = pack2(l[(kk0 + 4) * H1 + n], l[(kk0 + 5) * H1 + n]);
        w.w = pack2(l[(kk0 + 6) * H1 + n], l[(kk0 + 7) * H1 + n]);
        *(uint4*)(out + o) = w;
    }
}

// W2 -> [set][c][k0t] tiles of 64n x 64k bf16:
//   element (n<64, kk<64) at byte (n*128 + 2kk) ^ ((n&7)<<4)
__global__ __launch_bounds__(256)
void convert_w2(const float* __restrict__ W, const float* __restrict__ rW,
                ushort* __restrict__ dst)
{
    __shared__ float l[64 * H2];         // 16KB
    const int t   = threadIdx.x;
    const int k0t = blockIdx.x;          // 0..3
    const int c   = blockIdx.y;
    const int set = blockIdx.z;
    const float* src = (set ? rW : W) + ((size_t)c * H1 + k0t * 64) * H2;
    #pragma unroll
    for (int i = 0; i < 4; ++i)
        ((float4*)l)[i * 256 + t] = ((const float4*)src)[i * 256 + t];
    __syncthreads();
    char* out = (char*)dst + (((size_t)set * Cn + c) * 4 + k0t) * 8192;
    #pragma unroll
    for (int rd = 0; rd < 2; ++rd) {
        const int idx = rd * 256 + t;
        const int n = idx >> 3;                   // 0..63
        const int s = idx & 7;                    // 16B slot
        const int o = n * 128 + ((s << 4) ^ ((n & 7) << 4));
        const int kk0 = s * 8;
        uint4 w;
        w.x = pack2(l[(kk0 + 0) * H2 + n], l[(kk0 + 1) * H2 + n]);
        w.y = pack2(l[(kk0 + 2) * H2 + n], l[(kk0 + 3) * H2 + n]);
        w.z = pack2(l[(kk0 + 4) * H2 + n], l[(kk0 + 5) * H2 + n]);
        w.w = pack2(l[(kk0 + 6) * H2 + n], l[(kk0 + 7) * H2 + n]);
        *(uint4*)(out + o) = w;
    }
}

// ===================== Pass B: fused 256x256 8-phase MFMA kernel =====================
// LDS map (128KB): A[parity][rowhalf] 16KB at p*32768 + h*16384
//                  B[parity][khalf]  16KB at 65536 + p*32768 + kh*16384
// After K-loop the whole 128KB is reused: x1 bf16 [256][256] swizzled, then
// x2 f32 [256][68] @0, W3s f32 [64][17] @73728, x3 f32 [256][17] @81920.

__device__ __forceinline__ void stage_a(char* lds, const char* hbs_b, int p, int h,
                                        int kt, int bt0, int t) {
    const char* g = hbs_b + ((size_t)((bt0 + h * 2) * 12 + kt)) * 8192 + t * 16;
    char* l = lds + p * 32768 + h * 16384 + t * 16;
    load_lds16(g,         l);
    load_lds16(g + 98304, l + 8192);     // next row-tile: +12*8192 in src
}
__device__ __forceinline__ void stage_b(char* lds, const char* w1b, int p, int kh,
                                        int kt, int t) {
    const char* g = w1b + ((size_t)(kt * 2 + kh)) * 16384 + t * 16;
    char* l = lds + 65536 + p * 32768 + kh * 16384 + t * 16;
    load_lds16(g,        l);
    load_lds16(g + 8192, l + 8192);
}

template<int KS, int MH>
__device__ __forceinline__ void phase_reads(const char* lds, int p, int wr, int wc,
                                            int lrow, int lk, short8 breg[4], short8 areg[4]) {
    if (MH == 0) {
        #pragma unroll
        for (int nt = 0; nt < 4; ++nt) {
            const int col = wc * 64 + nt * 16 + lrow;
            breg[nt] = *(const short8*)(lds + 65536 + p * 32768 + KS * 16384
                          + col * 64 + ((2 * lk) ^ ((col & 3) << 4)));
        }
    }
    #pragma unroll
    for (int m4 = 0; m4 < 4; ++m4) {
        const int mt = MH * 4 + m4;
        const int ir = (mt & 3) * 16 + lrow;
        const int koff = KS * 64 + lk * 2;
        areg[m4] = *(const short8*)(lds + p * 32768 + (wr * 2 + (mt >> 2)) * 8192
                      + ir * 128 + (koff ^ ((ir & 7) << 4)));
    }
}

template<int MH>
__device__ __forceinline__ void phase_mfma(const short8 breg[4], const short8 areg[4],
                                           f32x4 acc[8][4]) {
    __builtin_amdgcn_s_setprio(1);
    #pragma unroll
    for (int m4 = 0; m4 < 4; ++m4)
        #pragma unroll
        for (int nt = 0; nt < 4; ++nt)
            acc[MH * 4 + m4][nt] = __builtin_amdgcn_mfma_f32_16x16x32_bf16(
                areg[m4], breg[nt], acc[MH * 4 + m4][nt], 0, 0, 0);
    __builtin_amdgcn_s_setprio(0);
}

__global__ __launch_bounds__(512, 2)
void scores_mfma_256(const ushort* __restrict__ hbs, const ushort* __restrict__ W1ts,
                     const ushort* __restrict__ W2ts,
                     const float* __restrict__ b1, const float* __restrict__ rb1,
                     const float* __restrict__ b2, const float* __restrict__ rb2,
                     const float* __restrict__ W3, const float* __restrict__ rW3,
                     const float* __restrict__ b3, const float* __restrict__ rb3,
                     const float* __restrict__ W4, const float* __restrict__ rW4,
                     const float* __restrict__ b4, const float* __restrict__ rb4,
                     const float* __restrict__ W5, const float* __restrict__ rW5,
                     const float* __restrict__ b5, const float* __restrict__ rb5,
                     float* __restrict__ scores)
{
    __shared__ uint4 smv[131072 / 16];
    char* lds = (char*)smv;

    const int t = threadIdx.x;
    const int wid = t >> 6, lane = t & 63;
    const int lrow = lane & 15;
    const int lkg  = lane >> 4;          // 0..3
    const int lk   = lkg * 8;
    const int wr = wid >> 2, wc = wid & 3;

    // bijective XCD swizzle, nwg = 2560
    const int cpx = 2560 >> 3;
    const int wg  = (blockIdx.x & 7) * cpx + (blockIdx.x >> 3);
    const int set = wg / 1280;
    const int rem = wg % 1280;
    const int c   = rem / 16;
    const int bt0 = (rem % 16) * 4;      // row-tile base (64-row tiles)

    const float* pb1 = set ? rb1 : b1;
    const float* pb2 = set ? rb2 : b2;
    const float* pW3 = set ? rW3 : W3;  const float* pb3 = set ? rb3 : b3;
    const float* pW4 = set ? rW4 : W4;  const float* pb4 = set ? rb4 : b4;
    const float* pW5 = set ? rW5 : W5;  const float* pb5 = set ? rb5 : b5;

    const char* hbs_b = (const char*)hbs;
    const char* w1b   = (const char*)W1ts + (size_t)(set * Cn + c) * 393216;

    f32x4 acc[8][4];
    #pragma unroll
    for (int i = 0; i < 8; ++i)
        #pragma unroll
        for (int j = 0; j < 4; ++j)
            acc[i][j] = (f32x4){0.f, 0.f, 0.f, 0.f};

    // -------- prologue: kt0 all 4 halves + kt1's B halves (12 loads)
    stage_a(lds, hbs_b, 0, 0, 0, bt0, t);
    stage_a(lds, hbs_b, 0, 1, 0, bt0, t);
    stage_b(lds, w1b, 0, 0, 0, t);
    stage_b(lds, w1b, 0, 1, 0, t);
    stage_b(lds, w1b, 1, 0, 1, t);
    stage_b(lds, w1b, 1, 1, 1, t);
    VMCNT4();                            // kt0 fully landed; kt1 B in flight
    BAR();

    short8 breg[4], areg[4];
    for (int j = 0; j < 12; ++j) {
        const int p  = j & 1;
        const int ja = (j + 1) % 12;     // wrap keeps vmcnt ledger uniform (dead slots)
        const int jb = (j + 2) % 12;
        // Ph1: ks0 b+a(0-3); stage A0(j+1)
        phase_reads<0, 0>(lds, p, wr, wc, lrow, lk, breg, areg);
        stage_a(lds, hbs_b, p ^ 1, 0, ja, bt0, t);
        BAR(); phase_mfma<0>(breg, areg, acc); BAR();
        // Ph2: ks0 a(4-7); stage A1(j+1)
        phase_reads<0, 1>(lds, p, wr, wc, lrow, lk, breg, areg);
        stage_a(lds, hbs_b, p ^ 1, 1, ja, bt0, t);
        BAR(); phase_mfma<1>(breg, areg, acc); BAR();
        // Ph3: ks1 b+a(0-3); stage Bk0(j+2)
        phase_reads<1, 0>(lds, p, wr, wc, lrow, lk, breg, areg);
        stage_b(lds, w1b, p, 0, jb, t);
        BAR(); phase_mfma<0>(breg, areg, acc); BAR();
        // Ph4: ks1 a(4-7); stage Bk1(j+2); counted wait
        phase_reads<1, 1>(lds, p, wr, wc, lrow, lk, breg, areg);
        stage_b(lds, w1b, p, 1, jb, t);
        VMCNT4();
        BAR(); phase_mfma<1>(breg, areg, acc); BAR();
    }
    VMCNT0();                            // drain wrapped stages before LDS reuse
    BAR();

    // -------- epilogue 1: bias + relu -> x1 bf16 [256][256] swizzled
    {
        const int crow0 = lkg * 4;
        float bias1[4];
        #pragma unroll
        for (int nt = 0; nt < 4; ++nt)
            bias1[nt] = pb1[(size_t)c * H1 + wc * 64 + nt * 16 + lrow];
        #pragma unroll
        for (int mt = 0; mt < 8; ++mt)
            #pragma unroll
            for (int nt = 0; nt < 4; ++nt)
                #pragma unroll
                for (int r = 0; r < 4; ++r) {
                    const int row = wr * 128 + mt * 16 + crow0 + r;
                    const int col = wc * 64 + nt * 16 + lrow;
                    const float v = fmaxf(acc[mt][nt][r] + bias1[nt], 0.f);
                    *(ushort*)(lds + ((row * 512 + col * 2) ^ ((row & 7) << 4))) = f2bf(v);
                }
    }
    BAR();

    // -------- layer 2: M=256 N=64 K=256; A from x1 LDS, B from global regs
    f32x4 acc2[2][4];
    #pragma unroll
    for (int i = 0; i < 2; ++i)
        #pragma unroll
        for (int j = 0; j < 4; ++j)
            acc2[i][j] = (f32x4){0.f, 0.f, 0.f, 0.f};
    {
        const char* w2b = (const char*)W2ts + (size_t)(set * Cn + c) * 32768;
        #pragma unroll
        for (int ksz = 0; ksz < 8; ++ksz) {
            short8 b2r[4], a2[2];
            const int kk = (ksz & 1) * 32 + lk;
            #pragma unroll
            for (int nt = 0; nt < 4; ++nt) {
                const int col = nt * 16 + lrow;
                b2r[nt] = *(const short8*)(w2b + (ksz >> 1) * 8192
                             + ((col * 128 + 2 * kk) ^ ((col & 7) << 4)));
            }
            const int k = ksz * 32 + lk;
            #pragma unroll
            for (int m2 = 0; m2 < 2; ++m2) {
                const int row = wid * 32 + m2 * 16 + lrow;
                a2[m2] = *(const short8*)(lds + ((row * 512 + 2 * k) ^ ((row & 7) << 4)));
            }
            #pragma unroll
            for (int m2 = 0; m2 < 2; ++m2)
                #pragma unroll
                for (int nt = 0; nt < 4; ++nt)
                    acc2[m2][nt] = __builtin_amdgcn_mfma_f32_16x16x32_bf16(
                        a2[m2], b2r[nt], acc2[m2][nt], 0, 0, 0);
        }
    }
    BAR();   // all x1 reads done; LDS free for x2/W3s

    // -------- epilogue 2: bias + relu -> x2 f32 [256][68] ; stage W3s [64][17]
    {
        const int crow0 = lkg * 4;
        #pragma unroll
        for (int nt = 0; nt < 4; ++nt) {
            const int col = nt * 16 + lrow;
            const float bb = pb2[(size_t)c * H2 + col];
            #pragma unroll
            for (int m2 = 0; m2 < 2; ++m2)
                #pragma unroll
                for (int r = 0; r < 4; ++r) {
                    const int row = wid * 32 + m2 * 16 + crow0 + r;
                    *(float*)(lds + row * 272 + col * 4) = fmaxf(acc2[m2][nt][r] + bb, 0.f);
                }
        }
        if (t < 256) {
            const int k = t >> 2, pq = (t & 3) * 4;
            const float4 v = *(const float4*)(pW3 + (size_t)c * (H2 * H3) + k * H3 + pq);
            *(float*)(lds + 73728 + (k * 17 + pq + 0) * 4) = v.x;
            *(float*)(lds + 73728 + (k * 17 + pq + 1) * 4) = v.y;
            *(float*)(lds + 73728 + (k * 17 + pq + 2) * 4) = v.z;
            *(float*)(lds + 73728 + (k * 17 + pq + 3) * 4) = v.w;
        }
    }
    BAR();

    // -------- layer 3: 64 -> 16 (2 threads per row)
    {
        const int row = t >> 1, ph = (t & 1) * 8;
        float a3[8];
        #pragma unroll
        for (int i = 0; i < 8; ++i) a3[i] = pb3[(size_t)c * H3 + ph + i];
        for (int k = 0; k < H2; ++k) {
            const float xv = *(const float*)(lds + row * 272 + k * 4);
            #pragma unroll
            for (int i = 0; i < 8; ++i)
                a3[i] = fmaf(xv, *(const float*)(lds + 73728 + (k * 17 + ph + i) * 4), a3[i]);
        }
        #pragma unroll
        for (int i = 0; i < 8; ++i)
            *(float*)(lds + 81920 + (row * 17 + ph + i) * 4) = a3[i];
    }
    BAR();

    // -------- layers 4-5: 16 -> 4 -> 1 -> sigmoid (1 thread per row)
    if (t < 256) {
        const int row = t;
        const float* w4c = pW4 + (size_t)c * (H3 * H4);
        float a4[4];
        #pragma unroll
        for (int o = 0; o < 4; ++o) a4[o] = pb4[(size_t)c * H4 + o];
        #pragma unroll
        for (int k = 0; k < H3; ++k) {
            const float xv = fmaxf(*(const float*)(lds + 81920 + (row * 17 + k) * 4), 0.f);
            #pragma unroll
            for (int o = 0; o < 4; ++o)
                a4[o] = fmaf(xv, w4c[k * H4 + o], a4[o]);
        }
        float x5 = pb5[c];
        #pragma unroll
        for (int k = 0; k < H4; ++k)
            x5 = fmaf(fmaxf(a4[k], 0.f), pW5[(size_t)c * H4 + k], x5);
        scores[((size_t)set * Bn + bt0 * 64 + row) * Cn + c] = 1.f / (1.f + expf(-x5));
    }
}

// ===================== loss kernels =====================
__device__ inline float bce_f(float p, float y) {
    p = fminf(fmaxf(p, 1e-8f), 1.0f - 1e-8f);
    return -(y * logf(p) + (1.f - y) * log1pf(-p));
}

__global__ __launch_bounds__(128)
void loss_kernel(const float* __restrict__ scores, const int* __restrict__ labels,
                 float* __restrict__ pair_sum, float* __restrict__ np_sum,
                 int* __restrict__ pair_cnt)
{
    __shared__ float ss[Cn], lt[Cn];
    __shared__ int lab[Cn];
    __shared__ float redf[128], redn[128];
    __shared__ int redi[128];

    const int b = blockIdx.x, t = threadIdx.x;
    float np_local = 0.f, ps_local = 0.f;
    int pc_local = 0;

    if (t < Cn) {
        const float s  = scores[(size_t)b * Cn + t];
        const float sr = scores[(size_t)Bn * Cn + (size_t)b * Cn + t];
        const int l = labels[(size_t)b * Cn + t];
        ss[t] = s; lab[t] = l;
        lt[t] = logf(s / (sr + 1e-8f) + 1e-8f);
        if (t >= 20) {
            const float y = (float)l;
            np_local = fmaxf(bce_f(s, y) - bce_f(sr, y) - 0.1f, 0.f);
        }
    }
    __syncthreads();
    if (t < Cn && lab[t] == 0) {
        const float sj = ss[t], ltj = lt[t];
        #pragma unroll
        for (int i = 0; i < 20; ++i) {
            if (lab[i] == 1 && sj >= ss[i]) {
                const float z = -(lt[i] - ltj);
                ps_local += fmaxf(z, 0.f) + log1pf(expf(-fabsf(z)));
                pc_local++;
            }
        }
    }
    redf[t] = ps_local; redn[t] = np_local; redi[t] = pc_local;
    __syncthreads();
    for (int s = 64; s > 0; s >>= 1) {
        if (t < s) { redf[t] += redf[t + s]; redn[t] += redn[t + s]; redi[t] += redi[t + s]; }
        __syncthreads();
    }
    if (t == 0) { pair_sum[b] = redf[0]; np_sum[b] = redn[0]; pair_cnt[b] = redi[0]; }
}

__global__ __launch_bounds__(256)
void final_kernel(const float* __restrict__ pair_sum, const int* __restrict__ pair_cnt,
                  const float* __restrict__ np_sum, float* __restrict__ out)
{
    __shared__ float r1[256], r2[256];
    __shared__ int ri[256];
    const int t = threadIdx.x;
    float s1 = 0.f, s2 = 0.f; int c1 = 0;
    for (int i = t; i < Bn; i += 256) { s1 += pair_sum[i]; c1 += pair_cnt[i]; s2 += np_sum[i]; }
    r1[t] = s1; r2[t] = s2; ri[t] = c1;
    __syncthreads();
    for (int s = 128; s > 0; s >>= 1) {
        if (t < s) { r1[t] += r1[t + s]; r2[t] += r2[t + s]; ri[t] += ri[t + s]; }
        __syncthreads();
    }
    if (t == 0) {
        const int n = ri[0];
        out[0] = (n > 0) ? (r1[0] / (float)(n > 1 ? n : 1)) : 0.f;
        out[1] = r2[0] / (float)(Bn * 60);
    }
}

// ===================== launch =====================
static inline size_t alup(size_t x) { return (x + 4095) & ~(size_t)4095; }

extern "C" void kernel_launch(void* const* d_in, const int* in_sizes, int n_in,
                              void* d_out, int out_size, void* d_ws, size_t ws_size,
                              hipStream_t stream)
{
    const float* hidden = (const float*)d_in[0];
    const int*   labels = (const int*)d_in[1];
    const float* W1 = (const float*)d_in[2];   const float* b1 = (const float*)d_in[3];
    const float* W2 = (const float*)d_in[4];   const float* b2 = (const float*)d_in[5];
    const float* W3 = (const float*)d_in[6];   const float* b3 = (const float*)d_in[7];
    const float* W4 = (const float*)d_in[8];   const float* b4 = (const float*)d_in[9];
    const float* W5 = (const float*)d_in[10];  const float* b5 = (const float*)d_in[11];
    const float* rW1 = (const float*)d_in[12]; const float* rb1 = (const float*)d_in[13];
    const float* rW2 = (const float*)d_in[14]; const float* rb2 = (const float*)d_in[15];
    const float* rW3 = (const float*)d_in[16]; const float* rb3 = (const float*)d_in[17];
    const float* rW4 = (const float*)d_in[18]; const float* rb4 = (const float*)d_in[19];
    const float* rW5 = (const float*)d_in[20]; const float* rb5 = (const float*)d_in[21];

    char* ws = (char*)d_ws;
    const size_t off_scores = 0;
    const size_t sz_scores  = (size_t)2 * Bn * Cn * 4;
    const size_t off_pair   = alup(off_scores + sz_scores);
    const size_t sz_pair    = (size_t)3 * Bn * 4;
    const size_t off_hbs    = alup(off_pair + sz_pair);
    const size_t sz_hbs     = (size_t)Bn * Dn * 2;
    const size_t off_w1t    = alup(off_hbs + sz_hbs);
    const size_t sz_w1t     = (size_t)2 * Cn * 24 * 16384;   // 62.9 MB
    const size_t off_w2t    = alup(off_w1t + sz_w1t);

    float* scoresb  = (float*)(ws + off_scores);
    float* pair_sum = (float*)(ws + off_pair);
    float* np_sum   = pair_sum + Bn;
    int*   pair_cnt = (int*)(np_sum + Bn);
    float* out      = (float*)d_out;

    ushort* hbs  = (ushort*)(ws + off_hbs);
    ushort* W1ts = (ushort*)(ws + off_w1t);
    ushort* W2ts = (ushort*)(ws + off_w2t);

    convert_hidden<<<dim3(12, Bn / 64), 256, 0, stream>>>(hidden, hbs);
    convert_w1<<<dim3(24, Cn, 2), 256, 0, stream>>>(W1, rW1, W1ts);
    convert_w2<<<dim3(4, Cn, 2), 256, 0, stream>>>(W2, rW2, W2ts);

    scores_mfma_256<<<2560, 512, 0, stream>>>(hbs, W1ts, W2ts,
        b1, rb1, b2, rb2, W3, rW3, b3, rb3, W4, rW4, b4, rb4, W5, rW5, b5, rb5,
        scoresb);
    loss_kernel<<<Bn, 128, 0, stream>>>(scoresb, labels, pair_sum, np_sum, pair_cnt);
    final_kernel<<<1, 256, 0, stream>>>(pair_sum, pair_cnt, np_sum, out);
}

// Round 5
// 353.594 us; speedup vs baseline: 17.7563x; 1.1460x over previous
//
#include <hip/hip_runtime.h>
#include <math.h>

typedef __attribute__((ext_vector_type(8))) short short8;
typedef __attribute__((ext_vector_type(4))) float f32x4;

#define Bn   4096
#define Dn   768
#define Cn   80
#define H1   256
#define H2   64
#define H3   16
#define H4   4

// fp32 -> bf16 RTNE
__device__ inline ushort f2bf(float f) {
    union { float f; unsigned u; } v; v.f = f;
    unsigned r = v.u + 0x7fffu + ((v.u >> 16) & 1u);
    return (ushort)(r >> 16);
}
__device__ inline unsigned pack2(float a, float b) {
    return (unsigned)f2bf(a) | ((unsigned)f2bf(b) << 16);
}
__device__ inline void load_lds16(const void* g, void* l) {
    __builtin_amdgcn_global_load_lds(
        (const __attribute__((address_space(1))) void*)g,
        (__attribute__((address_space(3))) void*)l, 16, 0, 0);
}

#define FENCE() asm volatile("" ::: "memory")
#define BAR() do { FENCE(); __builtin_amdgcn_sched_barrier(0); \
                   __builtin_amdgcn_s_barrier(); \
                   __builtin_amdgcn_sched_barrier(0); FENCE(); } while (0)
#define VMCNT4() do { asm volatile("s_waitcnt vmcnt(4)" ::: "memory"); \
                      __builtin_amdgcn_sched_barrier(0); } while (0)
#define VMCNT0() do { asm volatile("s_waitcnt vmcnt(0)" ::: "memory"); \
                      __builtin_amdgcn_sched_barrier(0); } while (0)

// ===================== Pass A: conversion kernels =====================
// hbs: per (b-tile64, k-tile64) 8KB tile, XOR-swizzled:
//   element (row r<64, k<64) at byte (r*128 + 2k) ^ ((r&7)<<4)
__global__ __launch_bounds__(256)
void convert_hidden(const float* __restrict__ hidden, ushort* __restrict__ hbs)
{
    const int t = threadIdx.x;
    const int kt = blockIdx.x;           // 0..11
    const int bt = blockIdx.y;           // 0..63
    char* out = (char*)(hbs + ((size_t)bt * 12 + kt) * 4096);
    #pragma unroll
    for (int ch = 0; ch < 2; ++ch) {
        const int o = (ch * 256 + t) * 16;
        const int row = o >> 7;
        const int slot = (o >> 4) & 7;
        const int ss = slot ^ (row & 7);
        const float* src = hidden + (size_t)(bt * 64 + row) * Dn + kt * 64 + ss * 8;
        const float4 f0 = ((const float4*)src)[0];
        const float4 f1 = ((const float4*)src)[1];
        uint4 w;
        w.x = pack2(f0.x, f0.y); w.y = pack2(f0.z, f0.w);
        w.z = pack2(f1.x, f1.y); w.w = pack2(f1.z, f1.w);
        *(uint4*)(out + o) = w;
    }
}

// W1 -> [set][c][kt*2+kh] tiles of 256n x 32k bf16, transposed & swizzled:
//   element (n<256, kk<32) at byte n*64 + (2kk ^ ((n&3)<<4))
__global__ __launch_bounds__(256)
void convert_w1(const float* __restrict__ W, const float* __restrict__ rW,
                ushort* __restrict__ dst)
{
    __shared__ float l[32 * H1];         // 32KB
    const int t   = threadIdx.x;
    const int kt2 = blockIdx.x;          // 0..23
    const int c   = blockIdx.y;
    const int set = blockIdx.z;
    const float* src = (set ? rW : W) + ((size_t)c * Dn + kt2 * 32) * H1;
    #pragma unroll
    for (int i = 0; i < 8; ++i)
        ((float4*)l)[i * 256 + t] = ((const float4*)src)[i * 256 + t];
    __syncthreads();
    char* out = (char*)dst + (((size_t)set * Cn + c) * 24 + kt2) * 16384;
    #pragma unroll
    for (int rd = 0; rd < 4; ++rd) {
        const int o = (rd * 256 + t) * 16;
        const int n = o >> 6;
        const int s = (o >> 4) & 3;
        const int kk0 = (s ^ (n & 3)) * 8;
        uint4 w;
        w.x = pack2(l[(kk0 + 0) * H1 + n], l[(kk0 + 1) * H1 + n]);
        w.y = pack2(l[(kk0 + 2) * H1 + n], l[(kk0 + 3) * H1 + n]);
        w.z = pack2(l[(kk0 + 4) * H1 + n], l[(kk0 + 5) * H1 + n]);
        w.w = pack2(l[(kk0 + 6) * H1 + n], l[(kk0 + 7) * H1 + n]);
        *(uint4*)(out + o) = w;
    }
}

// W2 -> [set][c][k0t] tiles of 64n x 64k bf16 (byte (n*128+2k)^((n&7)<<4))
// W3 -> [set][c] one tile 16n x 64k bf16 (same swizzle), 2KB
__global__ __launch_bounds__(256)
void convert_w23(const float* __restrict__ W2, const float* __restrict__ rW2,
                 const float* __restrict__ W3, const float* __restrict__ rW3,
                 ushort* __restrict__ dstW2, ushort* __restrict__ dstW3)
{
    __shared__ float l[64 * H2];         // 16KB
    const int t   = threadIdx.x;
    const int bx  = blockIdx.x;          // 0..4 : 0-3 = W2 chunk, 4 = W3
    const int c   = blockIdx.y;
    const int set = blockIdx.z;

    if (bx < 4) {
        const float* src = (set ? rW2 : W2) + ((size_t)c * H1 + bx * 64) * H2;
        #pragma unroll
        for (int i = 0; i < 4; ++i)
            ((float4*)l)[i * 256 + t] = ((const float4*)src)[i * 256 + t];
        __syncthreads();
        char* out = (char*)dstW2 + (((size_t)set * Cn + c) * 4 + bx) * 8192;
        #pragma unroll
        for (int rd = 0; rd < 2; ++rd) {
            const int idx = rd * 256 + t;
            const int n = idx >> 3;
            const int s = idx & 7;
            const int o = n * 128 + ((s << 4) ^ ((n & 7) << 4));
            const int kk0 = s * 8;
            uint4 w;
            w.x = pack2(l[(kk0 + 0) * H2 + n], l[(kk0 + 1) * H2 + n]);
            w.y = pack2(l[(kk0 + 2) * H2 + n], l[(kk0 + 3) * H2 + n]);
            w.z = pack2(l[(kk0 + 4) * H2 + n], l[(kk0 + 5) * H2 + n]);
            w.w = pack2(l[(kk0 + 6) * H2 + n], l[(kk0 + 7) * H2 + n]);
            *(uint4*)(out + o) = w;
        }
    } else if (t < 128) {
        // W3 (c,64,16) -> [16n][64k] swizzled bf16 tile
        const float* src = (set ? rW3 : W3) + (size_t)c * (H2 * H3);
        char* out = (char*)dstW3 + ((size_t)set * Cn + c) * 2048;
        const int o = t * 16;
        const int n = o >> 7;
        const int slot = (o >> 4) & 7;
        const int kk0 = (slot ^ (n & 7)) * 8;
        uint4 w;
        w.x = pack2(src[(kk0 + 0) * H3 + n], src[(kk0 + 1) * H3 + n]);
        w.y = pack2(src[(kk0 + 2) * H3 + n], src[(kk0 + 3) * H3 + n]);
        w.z = pack2(src[(kk0 + 4) * H3 + n], src[(kk0 + 5) * H3 + n]);
        w.w = pack2(src[(kk0 + 6) * H3 + n], src[(kk0 + 7) * H3 + n]);
        *(uint4*)(out + o) = w;
    }
}

// ===================== Pass B: fused 256x256 8-phase MFMA kernel =====================
// All MFMAs use SWAPPED operands: mfma(W-frag, X-frag, acc) so the acc fragment
// holds C^T: lane&15 = batch-row, (lane>>4)*4+r = output feature. This makes the
// epilogue a packed-b64 write along the feature dim.

__device__ __forceinline__ void stage_a(char* lds, const char* hbs_b, int p, int h,
                                        int kt, int bt0, int t) {
    const char* g = hbs_b + ((size_t)((bt0 + h * 2) * 12 + kt)) * 8192 + t * 16;
    char* l = lds + p * 32768 + h * 16384 + t * 16;
    load_lds16(g,         l);
    load_lds16(g + 98304, l + 8192);
}
__device__ __forceinline__ void stage_b(char* lds, const char* w1b, int p, int kh,
                                        int kt, int t) {
    const char* g = w1b + ((size_t)(kt * 2 + kh)) * 16384 + t * 16;
    char* l = lds + 65536 + p * 32768 + kh * 16384 + t * 16;
    load_lds16(g,        l);
    load_lds16(g + 8192, l + 8192);
}

template<int KS, int MH>
__device__ __forceinline__ void phase_reads(const char* lds, int p, int wr, int wc,
                                            int lrow, int lk, short8 breg[4], short8 areg[4]) {
    if (MH == 0) {
        #pragma unroll
        for (int nt = 0; nt < 4; ++nt) {
            const int col = wc * 64 + nt * 16 + lrow;
            breg[nt] = *(const short8*)(lds + 65536 + p * 32768 + KS * 16384
                          + col * 64 + ((2 * lk) ^ ((col & 3) << 4)));
        }
    }
    #pragma unroll
    for (int m4 = 0; m4 < 4; ++m4) {
        const int mt = MH * 4 + m4;
        const int ir = (mt & 3) * 16 + lrow;
        const int koff = KS * 64 + lk * 2;
        areg[m4] = *(const short8*)(lds + p * 32768 + (wr * 2 + (mt >> 2)) * 8192
                      + ir * 128 + (koff ^ ((ir & 7) << 4)));
    }
}

template<int MH>
__device__ __forceinline__ void phase_mfma(const short8 breg[4], const short8 areg[4],
                                           f32x4 acc[8][4]) {
    __builtin_amdgcn_s_setprio(1);
    #pragma unroll
    for (int m4 = 0; m4 < 4; ++m4)
        #pragma unroll
        for (int nt = 0; nt < 4; ++nt)
            acc[MH * 4 + m4][nt] = __builtin_amdgcn_mfma_f32_16x16x32_bf16(
                breg[nt], areg[m4], acc[MH * 4 + m4][nt], 0, 0, 0);   // swapped
    __builtin_amdgcn_s_setprio(0);
}

__global__ __launch_bounds__(512, 2)
void scores_mfma_256(const ushort* __restrict__ hbs, const ushort* __restrict__ W1ts,
                     const ushort* __restrict__ W2ts, const ushort* __restrict__ W3ts,
                     const float* __restrict__ b1, const float* __restrict__ rb1,
                     const float* __restrict__ b2, const float* __restrict__ rb2,
                     const float* __restrict__ b3, const float* __restrict__ rb3,
                     const float* __restrict__ W4, const float* __restrict__ rW4,
                     const float* __restrict__ b4, const float* __restrict__ rb4,
                     const float* __restrict__ W5, const float* __restrict__ rW5,
                     const float* __restrict__ b5, const float* __restrict__ rb5,
                     float* __restrict__ scores)
{
    __shared__ uint4 smv[131072 / 16];
    char* lds = (char*)smv;

    const int t = threadIdx.x;
    const int wid = t >> 6, lane = t & 63;
    const int lrow = lane & 15;
    const int lkg  = lane >> 4;          // 0..3
    const int lk   = lkg * 8;
    const int wr = wid >> 2, wc = wid & 3;

    // bijective XCD swizzle, nwg = 2560
    const int cpx = 2560 >> 3;
    const int wg  = (blockIdx.x & 7) * cpx + (blockIdx.x >> 3);
    const int set = wg / 1280;
    const int rem = wg % 1280;
    const int c   = rem / 16;
    const int bt0 = (rem % 16) * 4;

    const float* pb1 = set ? rb1 : b1;
    const float* pb2 = set ? rb2 : b2;
    const float* pb3 = set ? rb3 : b3;
    const float* pW4 = set ? rW4 : W4;  const float* pb4 = set ? rb4 : b4;
    const float* pW5 = set ? rW5 : W5;  const float* pb5 = set ? rb5 : b5;

    const char* hbs_b = (const char*)hbs;
    const char* w1b   = (const char*)W1ts + (size_t)(set * Cn + c) * 393216;

    f32x4 acc[8][4];
    #pragma unroll
    for (int i = 0; i < 8; ++i)
        #pragma unroll
        for (int j = 0; j < 4; ++j)
            acc[i][j] = (f32x4){0.f, 0.f, 0.f, 0.f};

    // -------- prologue
    stage_a(lds, hbs_b, 0, 0, 0, bt0, t);
    stage_a(lds, hbs_b, 0, 1, 0, bt0, t);
    stage_b(lds, w1b, 0, 0, 0, t);
    stage_b(lds, w1b, 0, 1, 0, t);
    stage_b(lds, w1b, 1, 0, 1, t);
    stage_b(lds, w1b, 1, 1, 1, t);
    VMCNT4();
    BAR();

    short8 breg[4], areg[4];
    for (int j = 0; j < 12; ++j) {
        const int p  = j & 1;
        const int ja = (j + 1) % 12;
        const int jb = (j + 2) % 12;
        phase_reads<0, 0>(lds, p, wr, wc, lrow, lk, breg, areg);
        stage_a(lds, hbs_b, p ^ 1, 0, ja, bt0, t);
        BAR(); phase_mfma<0>(breg, areg, acc); BAR();
        phase_reads<0, 1>(lds, p, wr, wc, lrow, lk, breg, areg);
        stage_a(lds, hbs_b, p ^ 1, 1, ja, bt0, t);
        BAR(); phase_mfma<1>(breg, areg, acc); BAR();
        phase_reads<1, 0>(lds, p, wr, wc, lrow, lk, breg, areg);
        stage_b(lds, w1b, p, 0, jb, t);
        BAR(); phase_mfma<0>(breg, areg, acc); BAR();
        phase_reads<1, 1>(lds, p, wr, wc, lrow, lk, breg, areg);
        stage_b(lds, w1b, p, 1, jb, t);
        VMCNT4();
        BAR(); phase_mfma<1>(breg, areg, acc); BAR();
    }
    VMCNT0();
    BAR();

    // -------- epilogue 1: bias + relu -> x1 bf16 [256 rows][256 h1] swizzled, b64 writes
    {
        float4 bias1[4];
        #pragma unroll
        for (int nt = 0; nt < 4; ++nt)
            bias1[nt] = *(const float4*)&pb1[(size_t)c * H1 + wc * 64 + nt * 16 + lkg * 4];
        #pragma unroll
        for (int mt = 0; mt < 8; ++mt) {
            const int row = wr * 128 + mt * 16 + lrow;
            const int swz = (row & 7) << 4;
            #pragma unroll
            for (int nt = 0; nt < 4; ++nt) {
                const float* bb = (const float*)&bias1[nt];
                uint2 w;
                w.x = pack2(fmaxf(acc[mt][nt][0] + bb[0], 0.f),
                            fmaxf(acc[mt][nt][1] + bb[1], 0.f));
                w.y = pack2(fmaxf(acc[mt][nt][2] + bb[2], 0.f),
                            fmaxf(acc[mt][nt][3] + bb[3], 0.f));
                const int off = row * 512 + ((wc * 128 + nt * 32 + lkg * 8) ^ swz);
                *(uint2*)(lds + off) = w;
            }
        }
    }
    BAR();

    // -------- layer 2: M=256 N=64 K=256 (swapped operands)
    f32x4 acc2[2][4];
    #pragma unroll
    for (int i = 0; i < 2; ++i)
        #pragma unroll
        for (int j = 0; j < 4; ++j)
            acc2[i][j] = (f32x4){0.f, 0.f, 0.f, 0.f};
    {
        const char* w2b = (const char*)W2ts + (size_t)(set * Cn + c) * 32768;
        #pragma unroll
        for (int ksz = 0; ksz < 8; ++ksz) {
            short8 b2r[4], a2[2];
            const int kk2 = (ksz & 1) * 32 + lk;
            #pragma unroll
            for (int nt = 0; nt < 4; ++nt) {
                const int col = nt * 16 + lrow;
                b2r[nt] = *(const short8*)(w2b + (ksz >> 1) * 8192
                             + ((col * 128 + 2 * kk2) ^ ((col & 7) << 4)));
            }
            const int k = ksz * 32 + lk;
            #pragma unroll
            for (int m2 = 0; m2 < 2; ++m2) {
                const int row = wid * 32 + m2 * 16 + lrow;
                a2[m2] = *(const short8*)(lds + ((row * 512 + 2 * k) ^ ((row & 7) << 4)));
            }
            #pragma unroll
            for (int m2 = 0; m2 < 2; ++m2)
                #pragma unroll
                for (int nt = 0; nt < 4; ++nt)
                    acc2[m2][nt] = __builtin_amdgcn_mfma_f32_16x16x32_bf16(
                        b2r[nt], a2[m2], acc2[m2][nt], 0, 0, 0);
        }
    }
    BAR();

    // -------- epilogue 2: bias + relu -> x2 bf16 [256 rows][64 h2] swizzled (32KB @0)
    {
        float4 bias2[4];
        #pragma unroll
        for (int nt = 0; nt < 4; ++nt)
            bias2[nt] = *(const float4*)&pb2[(size_t)c * H2 + nt * 16 + lkg * 4];
        #pragma unroll
        for (int m2 = 0; m2 < 2; ++m2) {
            const int row = wid * 32 + m2 * 16 + lrow;
            const int swz = (row & 7) << 4;
            #pragma unroll
            for (int nt = 0; nt < 4; ++nt) {
                const float* bb = (const float*)&bias2[nt];
                uint2 w;
                w.x = pack2(fmaxf(acc2[m2][nt][0] + bb[0], 0.f),
                            fmaxf(acc2[m2][nt][1] + bb[1], 0.f));
                w.y = pack2(fmaxf(acc2[m2][nt][2] + bb[2], 0.f),
                            fmaxf(acc2[m2][nt][3] + bb[3], 0.f));
                const int off = row * 128 + ((nt * 32 + lkg * 8) ^ swz);
                *(uint2*)(lds + off) = w;
            }
        }
    }
    BAR();

    // -------- layer 3: M=256 N=16 K=64 (MFMA, swapped); layers 4-5 in-register
    {
        const char* w3t = (const char*)W3ts + (size_t)(set * Cn + c) * 2048;
        short8 w3f[2];
        #pragma unroll
        for (int ks = 0; ks < 2; ++ks)
            w3f[ks] = *(const short8*)(w3t + lrow * 128
                         + ((2 * (ks * 32 + lk)) ^ ((lrow & 7) << 4)));
        f32x4 acc3[2];
        #pragma unroll
        for (int m2 = 0; m2 < 2; ++m2) acc3[m2] = (f32x4){0.f, 0.f, 0.f, 0.f};
        #pragma unroll
        for (int m2 = 0; m2 < 2; ++m2)
            #pragma unroll
            for (int ks = 0; ks < 2; ++ks) {
                const int row = wid * 32 + m2 * 16 + lrow;
                const short8 xf = *(const short8*)(lds + row * 128
                                     + ((2 * (ks * 32 + lk)) ^ ((row & 7) << 4)));
                acc3[m2] = __builtin_amdgcn_mfma_f32_16x16x32_bf16(
                    w3f[ks], xf, acc3[m2], 0, 0, 0);
            }

        // layers 4-5: h3 = lkg*4 + r is lane-local; sum over lkg via shfl_xor
        const float4 b3v = *(const float4*)&pb3[(size_t)c * H3 + lkg * 4];
        const float* w4c = pW4 + (size_t)c * (H3 * H4);
        float4 w4r[4];
        #pragma unroll
        for (int r = 0; r < 4; ++r)
            w4r[r] = *(const float4*)&w4c[(lkg * 4 + r) * H4];
        const float4 b4v = *(const float4*)&pb4[(size_t)c * H4];
        const float4 w5v = *(const float4*)&pW5[(size_t)c * H4];
        const float bb5 = pb5[c];

        #pragma unroll
        for (int m2 = 0; m2 < 2; ++m2) {
            float p4[4] = {0.f, 0.f, 0.f, 0.f};
            #pragma unroll
            for (int r = 0; r < 4; ++r) {
                const float x3 = fmaxf(acc3[m2][r] + ((const float*)&b3v)[r], 0.f);
                const float* wr4 = (const float*)&w4r[r];
                #pragma unroll
                for (int o = 0; o < 4; ++o)
                    p4[o] = fmaf(x3, wr4[o], p4[o]);
            }
            #pragma unroll
            for (int o = 0; o < 4; ++o) {
                p4[o] += __shfl_xor(p4[o], 16, 64);
                p4[o] += __shfl_xor(p4[o], 32, 64);
            }
            float x5 = bb5;
            #pragma unroll
            for (int o = 0; o < 4; ++o)
                x5 = fmaf(fmaxf(p4[o] + ((const float*)&b4v)[o], 0.f),
                          ((const float*)&w5v)[o], x5);
            const float sc = 1.f / (1.f + expf(-x5));
            if (lkg == 0)
                scores[((size_t)set * Bn + bt0 * 64 + wid * 32 + m2 * 16 + lrow) * Cn + c] = sc;
        }
    }
}

// ===================== loss kernels =====================
__device__ inline float bce_f(float p, float y) {
    p = fminf(fmaxf(p, 1e-8f), 1.0f - 1e-8f);
    return -(y * logf(p) + (1.f - y) * log1pf(-p));
}

__global__ __launch_bounds__(128)
void loss_kernel(const float* __restrict__ scores, const int* __restrict__ labels,
                 float* __restrict__ pair_sum, float* __restrict__ np_sum,
                 int* __restrict__ pair_cnt)
{
    __shared__ float ss[Cn], lt[Cn];
    __shared__ int lab[Cn];
    __shared__ float redf[128], redn[128];
    __shared__ int redi[128];

    const int b = blockIdx.x, t = threadIdx.x;
    float np_local = 0.f, ps_local = 0.f;
    int pc_local = 0;

    if (t < Cn) {
        const float s  = scores[(size_t)b * Cn + t];
        const float sr = scores[(size_t)Bn * Cn + (size_t)b * Cn + t];
        const int l = labels[(size_t)b * Cn + t];
        ss[t] = s; lab[t] = l;
        lt[t] = logf(s / (sr + 1e-8f) + 1e-8f);
        if (t >= 20) {
            const float y = (float)l;
            np_local = fmaxf(bce_f(s, y) - bce_f(sr, y) - 0.1f, 0.f);
        }
    }
    __syncthreads();
    if (t < Cn && lab[t] == 0) {
        const float sj = ss[t], ltj = lt[t];
        #pragma unroll
        for (int i = 0; i < 20; ++i) {
            if (lab[i] == 1 && sj >= ss[i]) {
                const float z = -(lt[i] - ltj);
                ps_local += fmaxf(z, 0.f) + log1pf(expf(-fabsf(z)));
                pc_local++;
            }
        }
    }
    redf[t] = ps_local; redn[t] = np_local; redi[t] = pc_local;
    __syncthreads();
    for (int s = 64; s > 0; s >>= 1) {
        if (t < s) { redf[t] += redf[t + s]; redn[t] += redn[t + s]; redi[t] += redi[t + s]; }
        __syncthreads();
    }
    if (t == 0) { pair_sum[b] = redf[0]; np_sum[b] = redn[0]; pair_cnt[b] = redi[0]; }
}

__global__ __launch_bounds__(1024)
void final_kernel(const float* __restrict__ pair_sum, const int* __restrict__ pair_cnt,
                  const float* __restrict__ np_sum, float* __restrict__ out)
{
    __shared__ float r1[1024], r2[1024];
    __shared__ int ri[1024];
    const int t = threadIdx.x;
    float s1 = 0.f, s2 = 0.f; int c1 = 0;
    for (int i = t; i < Bn; i += 1024) { s1 += pair_sum[i]; c1 += pair_cnt[i]; s2 += np_sum[i]; }
    r1[t] = s1; r2[t] = s2; ri[t] = c1;
    __syncthreads();
    for (int s = 512; s > 0; s >>= 1) {
        if (t < s) { r1[t] += r1[t + s]; r2[t] += r2[t + s]; ri[t] += ri[t + s]; }
        __syncthreads();
    }
    if (t == 0) {
        const int n = ri[0];
        out[0] = (n > 0) ? (r1[0] / (float)(n > 1 ? n : 1)) : 0.f;
        out[1] = r2[0] / (float)(Bn * 60);
    }
}

// ===================== launch =====================
static inline size_t alup(size_t x) { return (x + 4095) & ~(size_t)4095; }

extern "C" void kernel_launch(void* const* d_in, const int* in_sizes, int n_in,
                              void* d_out, int out_size, void* d_ws, size_t ws_size,
                              hipStream_t stream)
{
    const float* hidden = (const float*)d_in[0];
    const int*   labels = (const int*)d_in[1];
    const float* W1 = (const float*)d_in[2];   const float* b1 = (const float*)d_in[3];
    const float* W2 = (const float*)d_in[4];   const float* b2 = (const float*)d_in[5];
    const float* W3 = (const float*)d_in[6];   const float* b3 = (const float*)d_in[7];
    const float* W4 = (const float*)d_in[8];   const float* b4 = (const float*)d_in[9];
    const float* W5 = (const float*)d_in[10];  const float* b5 = (const float*)d_in[11];
    const float* rW1 = (const float*)d_in[12]; const float* rb1 = (const float*)d_in[13];
    const float* rW2 = (const float*)d_in[14]; const float* rb2 = (const float*)d_in[15];
    const float* rW3 = (const float*)d_in[16]; const float* rb3 = (const float*)d_in[17];
    const float* rW4 = (const float*)d_in[18]; const float* rb4 = (const float*)d_in[19];
    const float* rW5 = (const float*)d_in[20]; const float* rb5 = (const float*)d_in[21];

    char* ws = (char*)d_ws;
    const size_t off_scores = 0;
    const size_t sz_scores  = (size_t)2 * Bn * Cn * 4;
    const size_t off_pair   = alup(off_scores + sz_scores);
    const size_t sz_pair    = (size_t)3 * Bn * 4;
    const size_t off_hbs    = alup(off_pair + sz_pair);
    const size_t sz_hbs     = (size_t)Bn * Dn * 2;
    const size_t off_w1t    = alup(off_hbs + sz_hbs);
    const size_t sz_w1t     = (size_t)2 * Cn * 24 * 16384;
    const size_t off_w2t    = alup(off_w1t + sz_w1t);
    const size_t sz_w2t     = (size_t)2 * Cn * 4 * 8192;
    const size_t off_w3t    = alup(off_w2t + sz_w2t);

    float* scoresb  = (float*)(ws + off_scores);
    float* pair_sum = (float*)(ws + off_pair);
    float* np_sum   = pair_sum + Bn;
    int*   pair_cnt = (int*)(np_sum + Bn);
    float* out      = (float*)d_out;

    ushort* hbs  = (ushort*)(ws + off_hbs);
    ushort* W1ts = (ushort*)(ws + off_w1t);
    ushort* W2ts = (ushort*)(ws + off_w2t);
    ushort* W3ts = (ushort*)(ws + off_w3t);

    convert_hidden<<<dim3(12, Bn / 64), 256, 0, stream>>>(hidden, hbs);
    convert_w1<<<dim3(24, Cn, 2), 256, 0, stream>>>(W1, rW1, W1ts);
    convert_w23<<<dim3(5, Cn, 2), 256, 0, stream>>>(W2, rW2, W3, rW3, W2ts, W3ts);

    scores_mfma_256<<<2560, 512, 0, stream>>>(hbs, W1ts, W2ts, W3ts,
        b1, rb1, b2, rb2, b3, rb3, W4, rW4, b4, rb4, W5, rW5, b5, rb5,
        scoresb);
    loss_kernel<<<Bn, 128, 0, stream>>>(scoresb, labels, pair_sum, np_sum, pair_cnt);
    final_kernel<<<1, 1024, 0, stream>>>(pair_sum, pair_cnt, np_sum, out);
}